// Round 10
// baseline (694.099 us; speedup 1.0000x reference)
//
#include <hip/hip_runtime.h>

#define THREADS 256

typedef __bf16    bf16x8 __attribute__((ext_vector_type(8)));
typedef __bf16    bf16x4 __attribute__((ext_vector_type(4)));
typedef _Float16  f16x8  __attribute__((ext_vector_type(8)));
typedef float     f32x4  __attribute__((ext_vector_type(4)));

// ================= CSR build: histogram -> scan -> scatter =================

__global__ __launch_bounds__(THREADS) void k_hist(const int* __restrict__ dst,
                                                  int* __restrict__ cnt, int E) {
    int e = blockIdx.x * THREADS + threadIdx.x;
    if (e < E) atomicAdd(&cnt[dst[e]], 1);
}

__global__ __launch_bounds__(THREADS) void k_dinv(const int* __restrict__ cnt,
                                                  float* __restrict__ dinv, int n) {
    int i = blockIdx.x * THREADS + threadIdx.x;
    if (i < n) dinv[i] = rsqrtf((float)cnt[i] + 1.0f);
}

__global__ __launch_bounds__(THREADS) void k_scan1(const int* __restrict__ cnt,
                                                   int* __restrict__ rowptr,
                                                   int* __restrict__ blockSums, int n) {
    __shared__ int part[THREADS];
    int tid = threadIdx.x;
    int base = blockIdx.x * 1024 + tid * 4;
    int v0 = (base + 0 < n) ? cnt[base + 0] : 0;
    int v1 = (base + 1 < n) ? cnt[base + 1] : 0;
    int v2 = (base + 2 < n) ? cnt[base + 2] : 0;
    int v3 = (base + 3 < n) ? cnt[base + 3] : 0;
    part[tid] = v0 + v1 + v2 + v3;
    __syncthreads();
    for (int off = 1; off < THREADS; off <<= 1) {
        int t = 0;
        if (tid >= off) t = part[tid - off];
        __syncthreads();
        if (tid >= off) part[tid] += t;
        __syncthreads();
    }
    int excl = (tid == 0) ? 0 : part[tid - 1];
    if (tid == THREADS - 1) blockSums[blockIdx.x] = part[THREADS - 1];
    int run = excl;
    if (base + 0 < n) rowptr[base + 0] = run; run += v0;
    if (base + 1 < n) rowptr[base + 1] = run; run += v1;
    if (base + 2 < n) rowptr[base + 2] = run; run += v2;
    if (base + 3 < n) rowptr[base + 3] = run;
}

__global__ __launch_bounds__(THREADS) void k_scan2(int* __restrict__ blockSums,
                                                   int* __restrict__ rowptr,
                                                   int nchunks, int n, int E) {
    __shared__ int part[THREADS];
    int tid = threadIdx.x;
    int v = (tid < nchunks) ? blockSums[tid] : 0;
    part[tid] = v;
    __syncthreads();
    for (int off = 1; off < THREADS; off <<= 1) {
        int t = 0;
        if (tid >= off) t = part[tid - off];
        __syncthreads();
        if (tid >= off) part[tid] += t;
        __syncthreads();
    }
    int excl = (tid == 0) ? 0 : part[tid - 1];
    if (tid < nchunks) blockSums[tid] = excl;
    if (tid == 0) rowptr[n] = E;
}

__global__ __launch_bounds__(THREADS) void k_scan3(int* __restrict__ rowptr,
                                                   const int* __restrict__ blockSums, int n) {
    int i = blockIdx.x * THREADS + threadIdx.x;
    if (i < n) rowptr[i] += blockSums[i >> 10];
}

// writes: srcSorted (src id), swPair {src, dinv[src]}, dstSorted, edgePerm
__global__ __launch_bounds__(THREADS) void k_scatter(const int* __restrict__ src,
                                                     const int* __restrict__ dst,
                                                     const int* __restrict__ rowptr,
                                                     const float* __restrict__ dinv,
                                                     int* __restrict__ cursor,
                                                     int* __restrict__ srcSorted,
                                                     int2* __restrict__ swPair,
                                                     int* __restrict__ dstSorted,
                                                     int* __restrict__ edgePerm, int E) {
    int e = blockIdx.x * THREADS + threadIdx.x;
    if (e >= E) return;
    int d = dst[e];
    int s = src[e];
    int pos = rowptr[d] + atomicAdd(&cursor[d], 1);
    srcSorted[pos] = s;
    swPair[pos] = make_int2(s, __float_as_int(dinv[s]));
    dstSorted[pos] = d;
    edgePerm[pos] = e;
}

// ================= GEMM: C[M][128] = A[M][128] @ B[128][128]; also bf16 copy ====
__global__ __launch_bounds__(THREADS) void k_gemm128(const float* __restrict__ A,
                                                     const float* __restrict__ B,
                                                     float* __restrict__ C,
                                                     __bf16* __restrict__ C16, int M) {
    __shared__ float4 As[64][8];
    __shared__ float4 Bs[32][32];

    int tid = threadIdx.x;
    int tx = tid & 31;
    int ty = tid >> 5;
    int row0 = blockIdx.x * 64;

    float4 acc[8];
#pragma unroll
    for (int i = 0; i < 8; i++) acc[i] = make_float4(0.f, 0.f, 0.f, 0.f);

    for (int k0 = 0; k0 < 128; k0 += 32) {
#pragma unroll
        for (int i = 0; i < 2; i++) {
            int idx = tid + i * 256;
            int r = idx >> 3, q = idx & 7;
            int row = row0 + r;
            float4 v = make_float4(0.f, 0.f, 0.f, 0.f);
            if (row < M) v = *(const float4*)(A + (size_t)row * 128 + k0 + q * 4);
            As[r][q] = v;
        }
#pragma unroll
        for (int i = 0; i < 4; i++) {
            int idx = tid + i * 256;
            int r = idx >> 5, c4 = idx & 31;
            Bs[r][c4] = *(const float4*)(B + (size_t)(k0 + r) * 128 + c4 * 4);
        }
        __syncthreads();

#pragma unroll
        for (int k4 = 0; k4 < 8; k4++) {
            float4 b0 = Bs[k4 * 4 + 0][tx];
            float4 b1 = Bs[k4 * 4 + 1][tx];
            float4 b2 = Bs[k4 * 4 + 2][tx];
            float4 b3 = Bs[k4 * 4 + 3][tx];
#pragma unroll
            for (int i = 0; i < 8; i++) {
                float4 a = As[ty * 8 + i][k4];
                acc[i].x = fmaf(a.x, b0.x, fmaf(a.y, b1.x, fmaf(a.z, b2.x, fmaf(a.w, b3.x, acc[i].x))));
                acc[i].y = fmaf(a.x, b0.y, fmaf(a.y, b1.y, fmaf(a.z, b2.y, fmaf(a.w, b3.y, acc[i].y))));
                acc[i].z = fmaf(a.x, b0.z, fmaf(a.y, b1.z, fmaf(a.z, b2.z, fmaf(a.w, b3.z, acc[i].z))));
                acc[i].w = fmaf(a.x, b0.w, fmaf(a.y, b1.w, fmaf(a.z, b2.w, fmaf(a.w, b3.w, acc[i].w))));
            }
        }
        __syncthreads();
    }

#pragma unroll
    for (int i = 0; i < 8; i++) {
        int row = row0 + ty * 8 + i;
        if (row < M) {
            *(float4*)(C + (size_t)row * 128 + tx * 4) = acc[i];
            bf16x4 c16;
            c16[0] = (__bf16)acc[i].x; c16[1] = (__bf16)acc[i].y;
            c16[2] = (__bf16)acc[i].z; c16[3] = (__bf16)acc[i].w;
            *(bf16x4*)(C16 + (size_t)row * 128 + tx * 4) = c16;
        }
    }
}

// ================= gather-aggregate (bf16 gather, fused finalize, f32+f16 out) ====
__global__ __launch_bounds__(THREADS) void k_gather_agg(const int* __restrict__ rowptr,
                                                        const int2* __restrict__ swPair,
                                                        const __bf16* __restrict__ xw16,
                                                        const float* __restrict__ xw,
                                                        const float* __restrict__ dinv,
                                                        const float* __restrict__ bias,
                                                        float* __restrict__ h,
                                                        _Float16* __restrict__ h16, int n) {
    int node = blockIdx.x * 4 + (threadIdx.x >> 6);
    int lane = threadIdx.x & 63;
    int q = lane >> 4;
    int c = lane & 15;          // channels c*8 .. c*8+7
    if (node >= n) return;
    int beg = rowptr[node], end = rowptr[node + 1];
    float di = dinv[node];

    float acc[8];
#pragma unroll
    for (int i = 0; i < 8; i++) acc[i] = 0.f;

    int j = beg;
    for (; j + 15 < end; j += 16) {
        int2 pw0 = swPair[j + q];
        int2 pw1 = swPair[j + 4 + q];
        int2 pw2 = swPair[j + 8 + q];
        int2 pw3 = swPair[j + 12 + q];
        bf16x8 v0 = *(const bf16x8*)(xw16 + (size_t)pw0.x * 128 + c * 8);
        bf16x8 v1 = *(const bf16x8*)(xw16 + (size_t)pw1.x * 128 + c * 8);
        bf16x8 v2 = *(const bf16x8*)(xw16 + (size_t)pw2.x * 128 + c * 8);
        bf16x8 v3 = *(const bf16x8*)(xw16 + (size_t)pw3.x * 128 + c * 8);
        float w0 = __int_as_float(pw0.y);
        float w1 = __int_as_float(pw1.y);
        float w2 = __int_as_float(pw2.y);
        float w3 = __int_as_float(pw3.y);
#pragma unroll
        for (int i = 0; i < 8; i++) {
            acc[i] = fmaf((float)v0[i], w0, acc[i]);
            acc[i] = fmaf((float)v1[i], w1, acc[i]);
            acc[i] = fmaf((float)v2[i], w2, acc[i]);
            acc[i] = fmaf((float)v3[i], w3, acc[i]);
        }
    }
    for (; j + 7 < end; j += 8) {
        int2 pw0 = swPair[j + q];
        int2 pw1 = swPair[j + 4 + q];
        bf16x8 v0 = *(const bf16x8*)(xw16 + (size_t)pw0.x * 128 + c * 8);
        bf16x8 v1 = *(const bf16x8*)(xw16 + (size_t)pw1.x * 128 + c * 8);
        float w0 = __int_as_float(pw0.y);
        float w1 = __int_as_float(pw1.y);
#pragma unroll
        for (int i = 0; i < 8; i++) {
            acc[i] = fmaf((float)v0[i], w0, acc[i]);
            acc[i] = fmaf((float)v1[i], w1, acc[i]);
        }
    }
    for (; j + 3 < end; j += 4) {
        int2 pw = swPair[j + q];
        bf16x8 v = *(const bf16x8*)(xw16 + (size_t)pw.x * 128 + c * 8);
        float w = __int_as_float(pw.y);
#pragma unroll
        for (int i = 0; i < 8; i++) acc[i] = fmaf((float)v[i], w, acc[i]);
    }
    int rem = end - j;
    if (q < rem) {
        int2 pw = swPair[j + q];
        bf16x8 v = *(const bf16x8*)(xw16 + (size_t)pw.x * 128 + c * 8);
        float w = __int_as_float(pw.y);
#pragma unroll
        for (int i = 0; i < 8; i++) acc[i] = fmaf((float)v[i], w, acc[i]);
    }

    // merge quarters
#pragma unroll
    for (int i = 0; i < 8; i++) {
        acc[i] += __shfl_xor(acc[i], 16);
        acc[i] += __shfl_xor(acc[i], 32);
    }

    if (q == 0) {
        float4 xv0 = *(const float4*)(xw + (size_t)node * 128 + c * 8);
        float4 xv1 = *(const float4*)(xw + (size_t)node * 128 + c * 8 + 4);
        float4 b0 = *(const float4*)(bias + c * 8);
        float4 b1 = *(const float4*)(bias + c * 8 + 4);
        float dd = di * di;
        float r[8];
        r[0] = fmaxf(fmaf(acc[0], di, fmaf(xv0.x, dd, b0.x)), 0.f);
        r[1] = fmaxf(fmaf(acc[1], di, fmaf(xv0.y, dd, b0.y)), 0.f);
        r[2] = fmaxf(fmaf(acc[2], di, fmaf(xv0.z, dd, b0.z)), 0.f);
        r[3] = fmaxf(fmaf(acc[3], di, fmaf(xv0.w, dd, b0.w)), 0.f);
        r[4] = fmaxf(fmaf(acc[4], di, fmaf(xv1.x, dd, b1.x)), 0.f);
        r[5] = fmaxf(fmaf(acc[5], di, fmaf(xv1.y, dd, b1.y)), 0.f);
        r[6] = fmaxf(fmaf(acc[6], di, fmaf(xv1.z, dd, b1.z)), 0.f);
        r[7] = fmaxf(fmaf(acc[7], di, fmaf(xv1.w, dd, b1.w)), 0.f);
        *(float4*)(h + (size_t)node * 128 + c * 8)     = make_float4(r[0], r[1], r[2], r[3]);
        *(float4*)(h + (size_t)node * 128 + c * 8 + 4) = make_float4(r[4], r[5], r[6], r[7]);
        f16x8 r16;
#pragma unroll
        for (int i = 0; i < 8; i++) r16[i] = (_Float16)r[i];
        *(f16x8*)(h16 + (size_t)node * 128 + c * 8) = r16;
    }
}

// ================= B-pack: fc1w [256][128] f32 -> MFMA B-fragments fp16 =================
__global__ __launch_bounds__(THREADS) void k_pack_b(const float* __restrict__ fc1w,
                                                    _Float16* __restrict__ bpack) {
    int t = blockIdx.x * THREADS + threadIdx.x;   // 0..4095
    int lane = t & 63;
    int fi = t >> 6;          // ks*8+nt
    int nt = fi & 7, ks = fi >> 3;
    int krow = ks * 32 + (lane >> 4) * 8;
    int col = nt * 16 + (lane & 15);
    f16x8 v;
#pragma unroll
    for (int i = 0; i < 8; i++) v[i] = (_Float16)fc1w[(size_t)(krow + i) * 128 + col];
    *(f16x8*)(bpack + (size_t)t * 8) = v;
}

// ================= edge head (MFMA fp16, dst-sorted, 2 A-tiles/wave) ============
// 4 waves/block, 32 sorted-edges/wave (2 MFMA A-tiles). Each B fragment is
// loaded once and feeds BOTH tiles' MFMAs -> B L1/L2 traffic per edge halved.
__global__ __launch_bounds__(THREADS) void k_edge_head_mfma(const int* __restrict__ srcSorted,
                                                            const int* __restrict__ dstSorted,
                                                            const int* __restrict__ edgePerm,
                                                            const _Float16* __restrict__ h16,
                                                            const _Float16* __restrict__ bpack,
                                                            const float* __restrict__ fc1b,
                                                            const float* __restrict__ fc2w,
                                                            const float* __restrict__ fc2b,
                                                            float* __restrict__ out, int E) {
    int tid = threadIdx.x;
    int w = tid >> 6;
    int lane = tid & 63;
    int m = lane & 15;        // A row (edge within tile)
    int kg = lane >> 4;       // k-group: feature = ks*32 + kg*8 + i
    int e0w = blockIdx.x * 128 + w * 32;
    int p0 = e0w + m;         // tile-0 sorted position
    int p1 = e0w + 16 + m;    // tile-1 sorted position
    bool v0 = p0 < E, v1 = p1 < E;
    int s0 = v0 ? srcSorted[p0] : 0;
    int d0 = v0 ? dstSorted[p0] : 0;
    int s1 = v1 ? srcSorted[p1] : 0;
    int d1 = v1 ? dstSorted[p1] : 0;
    const _Float16* px0 = h16 + (size_t)s0 * 128 + kg * 8;
    const _Float16* py0 = h16 + (size_t)d0 * 128 + kg * 8;
    const _Float16* px1 = h16 + (size_t)s1 * 128 + kg * 8;
    const _Float16* py1 = h16 + (size_t)d1 * 128 + kg * 8;

    // issue all 16 gathers first (ILP)
    f16x8 xl0[4], yl0[4], xl1[4], yl1[4];
#pragma unroll
    for (int ks = 0; ks < 4; ks++) {
        xl0[ks] = *(const f16x8*)(px0 + ks * 32);
        yl0[ks] = *(const f16x8*)(py0 + ks * 32);
        xl1[ks] = *(const f16x8*)(px1 + ks * 32);
        yl1[ks] = *(const f16x8*)(py1 + ks * 32);
    }

    // packed fp16 prod/diff -> A fragments (xl/yl die here)
    f16x8 a0[8], a1[8];
#pragma unroll
    for (int ks = 0; ks < 4; ks++) {
        a0[ks]     = xl0[ks] * yl0[ks];
        a0[ks + 4] = xl0[ks] - yl0[ks];
        a1[ks]     = xl1[ks] * yl1[ks];
        a1[ks + 4] = xl1[ks] - yl1[ks];
    }

    f32x4 acc0[8], acc1[8];
#pragma unroll
    for (int i = 0; i < 8; i++) {
        acc0[i] = (f32x4){0.f, 0.f, 0.f, 0.f};
        acc1[i] = (f32x4){0.f, 0.f, 0.f, 0.f};
    }

    const f16x8* bfr = ((const f16x8*)bpack) + lane;
#pragma unroll
    for (int ks = 0; ks < 8; ks++) {
#pragma unroll
        for (int nt = 0; nt < 8; nt++) {
            f16x8 b = bfr[(size_t)(ks * 8 + nt) * 64];
            acc0[nt] = __builtin_amdgcn_mfma_f32_16x16x32_f16(a0[ks], b, acc0[nt], 0, 0, 0);
            acc1[nt] = __builtin_amdgcn_mfma_f32_16x16x32_f16(a1[ks], b, acc1[nt], 0, 0, 0);
        }
    }

    // epilogue: lane holds cols n = nt*16 + (lane&15), rows m = (lane>>4)*4 + r
    int n0 = lane & 15;
    int rowg = lane >> 4;
    float part0[4] = {0.f, 0.f, 0.f, 0.f};
    float part1[4] = {0.f, 0.f, 0.f, 0.f};
#pragma unroll
    for (int nt = 0; nt < 8; nt++) {
        float bb = fc1b[nt * 16 + n0];
        float ww = fc2w[nt * 16 + n0];
#pragma unroll
        for (int r = 0; r < 4; r++) {
            float z0 = fmaxf(acc0[nt][r] + bb, 0.f);
            float z1 = fmaxf(acc1[nt][r] + bb, 0.f);
            part0[r] = fmaf(z0, ww, part0[r]);
            part1[r] = fmaf(z1, ww, part1[r]);
        }
    }
#pragma unroll
    for (int r = 0; r < 4; r++) {
        part0[r] += __shfl_xor(part0[r], 1);
        part0[r] += __shfl_xor(part0[r], 2);
        part0[r] += __shfl_xor(part0[r], 4);
        part0[r] += __shfl_xor(part0[r], 8);
        part1[r] += __shfl_xor(part1[r], 1);
        part1[r] += __shfl_xor(part1[r], 2);
        part1[r] += __shfl_xor(part1[r], 4);
        part1[r] += __shfl_xor(part1[r], 8);
    }
    if (n0 == 0) {
        float b2 = fc2b[0];
#pragma unroll
        for (int r = 0; r < 4; r++) {
            int q0 = e0w + rowg * 4 + r;
            int q1 = q0 + 16;
            if (q0 < E) out[edgePerm[q0]] = 1.0f / (1.0f + expf(-(part0[r] + b2)));
            if (q1 < E) out[edgePerm[q1]] = 1.0f / (1.0f + expf(-(part1[r] + b2)));
        }
    }
}

// ================= host =================
extern "C" void kernel_launch(void* const* d_in, const int* in_sizes, int n_in,
                              void* d_out, int out_size, void* d_ws, size_t ws_size,
                              hipStream_t stream) {
    const float* x    = (const float*)d_in[0];
    const int*   ei   = (const int*)d_in[1];
    const float* W1   = (const float*)d_in[2];
    const float* b1   = (const float*)d_in[3];
    const float* W2   = (const float*)d_in[4];
    const float* b2   = (const float*)d_in[5];
    const float* fc1w = (const float*)d_in[6];
    const float* fc1b = (const float*)d_in[7];
    const float* fc2w = (const float*)d_in[8];
    const float* fc2b = (const float*)d_in[9];

    int N = in_sizes[0] / 128;
    int E = in_sizes[1] / 2;
    const int* src = ei;
    const int* dst = ei + E;

    // ---- workspace layout ----
    char* ws = (char*)d_ws;
    size_t off = 0;
    auto alloc = [&](size_t bytes) { char* p = ws + off; off += (bytes + 255) & ~(size_t)255; return p; };
    int*      cnt       = (int*)     alloc((size_t)N * 4);
    int*      rowptr    = (int*)     alloc(((size_t)N + 1) * 4);
    int*      cursor    = (int*)     alloc((size_t)N * 4);
    int*      blockSums = (int*)     alloc(256 * 4);
    int*      srcSorted = (int*)     alloc((size_t)E * 4);
    int2*     swPair    = (int2*)    alloc((size_t)E * 8);
    int*      dstSorted = (int*)     alloc((size_t)E * 4);
    int*      edgePerm  = (int*)     alloc((size_t)E * 4);
    float*    dinv      = (float*)   alloc((size_t)N * 4);
    _Float16* bpack     = (_Float16*)alloc((size_t)4096 * 8 * 2);     // 64 KB
    float*    xw        = (float*)   alloc((size_t)N * 128 * 4);
    __bf16*   xw16      = (__bf16*)  alloc((size_t)N * 128 * 2);
    float*    h         = (float*)   alloc((size_t)N * 128 * 4);
    _Float16* h16       = (_Float16*)alloc((size_t)N * 128 * 2);

    int gN     = (N + THREADS - 1) / THREADS;
    int gE     = (E + THREADS - 1) / THREADS;
    int nchunk = (N + 1023) / 1024;
    int gGemm  = (N + 63) / 64;
    int gGath  = (N + 3) / 4;
    int gHead  = (E + 127) / 128;

    // ---- CSR build + degrees + B-pack ----
    hipMemsetAsync(cnt, 0, (size_t)N * 4, stream);
    k_hist<<<gE, THREADS, 0, stream>>>(dst, cnt, E);
    k_dinv<<<gN, THREADS, 0, stream>>>(cnt, dinv, N);
    k_scan1<<<nchunk, THREADS, 0, stream>>>(cnt, rowptr, blockSums, N);
    k_scan2<<<1, THREADS, 0, stream>>>(blockSums, rowptr, nchunk, N, E);
    k_scan3<<<gN, THREADS, 0, stream>>>(rowptr, blockSums, N);
    hipMemsetAsync(cursor, 0, (size_t)N * 4, stream);
    k_scatter<<<gE, THREADS, 0, stream>>>(src, dst, rowptr, dinv, cursor,
                                          srcSorted, swPair, dstSorted, edgePerm, E);
    k_pack_b<<<16, THREADS, 0, stream>>>(fc1w, bpack);

    // ---- layer 1 ----
    k_gemm128<<<gGemm, THREADS, 0, stream>>>(x, W1, xw, xw16, N);
    k_gather_agg<<<gGath, THREADS, 0, stream>>>(rowptr, swPair, xw16, xw, dinv, b1, h, h16, N);

    // ---- layer 2 ----
    k_gemm128<<<gGemm, THREADS, 0, stream>>>(h, W2, xw, xw16, N);
    k_gather_agg<<<gGath, THREADS, 0, stream>>>(rowptr, swPair, xw16, xw, dinv, b2, h, h16, N);

    // ---- edge head (MFMA fp16, sorted order, 2 A-tiles/wave) ----
    k_edge_head_mfma<<<gHead, THREADS, 0, stream>>>(srcSorted, dstSorted, edgePerm,
                                                    h16, bpack, fc1b, fc2w, fc2b,
                                                    (float*)d_out, E);
}

// Round 11
// 648.263 us; speedup vs baseline: 1.0707x; 1.0707x over previous
//
#include <hip/hip_runtime.h>

#define THREADS 256

typedef __bf16    bf16x8 __attribute__((ext_vector_type(8)));
typedef __bf16    bf16x4 __attribute__((ext_vector_type(4)));
typedef _Float16  f16x8  __attribute__((ext_vector_type(8)));
typedef float     f32x4  __attribute__((ext_vector_type(4)));

// ================= CSR build: histogram -> scan -> scatter =================

__global__ __launch_bounds__(THREADS) void k_hist(const int* __restrict__ dst,
                                                  int* __restrict__ cnt, int E) {
    int e = blockIdx.x * THREADS + threadIdx.x;
    if (e < E) atomicAdd(&cnt[dst[e]], 1);
}

__global__ __launch_bounds__(THREADS) void k_dinv(const int* __restrict__ cnt,
                                                  float* __restrict__ dinv, int n) {
    int i = blockIdx.x * THREADS + threadIdx.x;
    if (i < n) dinv[i] = rsqrtf((float)cnt[i] + 1.0f);
}

__global__ __launch_bounds__(THREADS) void k_scan1(const int* __restrict__ cnt,
                                                   int* __restrict__ rowptr,
                                                   int* __restrict__ blockSums, int n) {
    __shared__ int part[THREADS];
    int tid = threadIdx.x;
    int base = blockIdx.x * 1024 + tid * 4;
    int v0 = (base + 0 < n) ? cnt[base + 0] : 0;
    int v1 = (base + 1 < n) ? cnt[base + 1] : 0;
    int v2 = (base + 2 < n) ? cnt[base + 2] : 0;
    int v3 = (base + 3 < n) ? cnt[base + 3] : 0;
    part[tid] = v0 + v1 + v2 + v3;
    __syncthreads();
    for (int off = 1; off < THREADS; off <<= 1) {
        int t = 0;
        if (tid >= off) t = part[tid - off];
        __syncthreads();
        if (tid >= off) part[tid] += t;
        __syncthreads();
    }
    int excl = (tid == 0) ? 0 : part[tid - 1];
    if (tid == THREADS - 1) blockSums[blockIdx.x] = part[THREADS - 1];
    int run = excl;
    if (base + 0 < n) rowptr[base + 0] = run; run += v0;
    if (base + 1 < n) rowptr[base + 1] = run; run += v1;
    if (base + 2 < n) rowptr[base + 2] = run; run += v2;
    if (base + 3 < n) rowptr[base + 3] = run;
}

__global__ __launch_bounds__(THREADS) void k_scan2(int* __restrict__ blockSums,
                                                   int* __restrict__ rowptr,
                                                   int nchunks, int n, int E) {
    __shared__ int part[THREADS];
    int tid = threadIdx.x;
    int v = (tid < nchunks) ? blockSums[tid] : 0;
    part[tid] = v;
    __syncthreads();
    for (int off = 1; off < THREADS; off <<= 1) {
        int t = 0;
        if (tid >= off) t = part[tid - off];
        __syncthreads();
        if (tid >= off) part[tid] += t;
        __syncthreads();
    }
    int excl = (tid == 0) ? 0 : part[tid - 1];
    if (tid < nchunks) blockSums[tid] = excl;
    if (tid == 0) rowptr[n] = E;
}

__global__ __launch_bounds__(THREADS) void k_scan3(int* __restrict__ rowptr,
                                                   const int* __restrict__ blockSums, int n) {
    int i = blockIdx.x * THREADS + threadIdx.x;
    if (i < n) rowptr[i] += blockSums[i >> 10];
}

// writes: swPair {src, dinv[src]}, sdSorted {src,dst}, edgePerm
__global__ __launch_bounds__(THREADS) void k_scatter(const int* __restrict__ src,
                                                     const int* __restrict__ dst,
                                                     const int* __restrict__ rowptr,
                                                     const float* __restrict__ dinv,
                                                     int* __restrict__ cursor,
                                                     int2* __restrict__ swPair,
                                                     int2* __restrict__ sdSorted,
                                                     int* __restrict__ edgePerm, int E) {
    int e = blockIdx.x * THREADS + threadIdx.x;
    if (e >= E) return;
    int d = dst[e];
    int s = src[e];
    int pos = rowptr[d] + atomicAdd(&cursor[d], 1);
    swPair[pos] = make_int2(s, __float_as_int(dinv[s]));
    sdSorted[pos] = make_int2(s, d);
    edgePerm[pos] = e;
}

// ================= GEMM (f32 A): C[M][128] = A[M][128] @ B[128][128] ============
__global__ __launch_bounds__(THREADS) void k_gemm128_f32(const float* __restrict__ A,
                                                         const float* __restrict__ B,
                                                         float* __restrict__ C,
                                                         __bf16* __restrict__ C16, int M) {
    __shared__ float4 As[64][8];
    __shared__ float4 Bs[32][32];

    int tid = threadIdx.x;
    int tx = tid & 31;
    int ty = tid >> 5;
    int row0 = blockIdx.x * 64;

    float4 acc[8];
#pragma unroll
    for (int i = 0; i < 8; i++) acc[i] = make_float4(0.f, 0.f, 0.f, 0.f);

    for (int k0 = 0; k0 < 128; k0 += 32) {
#pragma unroll
        for (int i = 0; i < 2; i++) {
            int idx = tid + i * 256;
            int r = idx >> 3, q = idx & 7;
            int row = row0 + r;
            float4 v = make_float4(0.f, 0.f, 0.f, 0.f);
            if (row < M) v = *(const float4*)(A + (size_t)row * 128 + k0 + q * 4);
            As[r][q] = v;
        }
#pragma unroll
        for (int i = 0; i < 4; i++) {
            int idx = tid + i * 256;
            int r = idx >> 5, c4 = idx & 31;
            Bs[r][c4] = *(const float4*)(B + (size_t)(k0 + r) * 128 + c4 * 4);
        }
        __syncthreads();

#pragma unroll
        for (int k4 = 0; k4 < 8; k4++) {
            float4 b0 = Bs[k4 * 4 + 0][tx];
            float4 b1 = Bs[k4 * 4 + 1][tx];
            float4 b2 = Bs[k4 * 4 + 2][tx];
            float4 b3 = Bs[k4 * 4 + 3][tx];
#pragma unroll
            for (int i = 0; i < 8; i++) {
                float4 a = As[ty * 8 + i][k4];
                acc[i].x = fmaf(a.x, b0.x, fmaf(a.y, b1.x, fmaf(a.z, b2.x, fmaf(a.w, b3.x, acc[i].x))));
                acc[i].y = fmaf(a.x, b0.y, fmaf(a.y, b1.y, fmaf(a.z, b2.y, fmaf(a.w, b3.y, acc[i].y))));
                acc[i].z = fmaf(a.x, b0.z, fmaf(a.y, b1.z, fmaf(a.z, b2.z, fmaf(a.w, b3.z, acc[i].z))));
                acc[i].w = fmaf(a.x, b0.w, fmaf(a.y, b1.w, fmaf(a.z, b2.w, fmaf(a.w, b3.w, acc[i].w))));
            }
        }
        __syncthreads();
    }

#pragma unroll
    for (int i = 0; i < 8; i++) {
        int row = row0 + ty * 8 + i;
        if (row < M) {
            *(float4*)(C + (size_t)row * 128 + tx * 4) = acc[i];
            bf16x4 c16;
            c16[0] = (__bf16)acc[i].x; c16[1] = (__bf16)acc[i].y;
            c16[2] = (__bf16)acc[i].z; c16[3] = (__bf16)acc[i].w;
            *(bf16x4*)(C16 + (size_t)row * 128 + tx * 4) = c16;
        }
    }
}

// ================= GEMM (fp16 A): same, A staged from h16 with convert =========
__global__ __launch_bounds__(THREADS) void k_gemm128_f16(const _Float16* __restrict__ A,
                                                         const float* __restrict__ B,
                                                         float* __restrict__ C,
                                                         __bf16* __restrict__ C16, int M) {
    __shared__ float4 As[64][8];
    __shared__ float4 Bs[32][32];

    int tid = threadIdx.x;
    int tx = tid & 31;
    int ty = tid >> 5;
    int row0 = blockIdx.x * 64;

    float4 acc[8];
#pragma unroll
    for (int i = 0; i < 8; i++) acc[i] = make_float4(0.f, 0.f, 0.f, 0.f);

    for (int k0 = 0; k0 < 128; k0 += 32) {
        // stage A: 64 rows x 32 k from fp16 (256 threads x 8 elems)
        {
            int r = tid >> 2, q = tid & 3;     // q = 8-elem chunk
            int row = row0 + r;
            f16x8 v;
            if (row < M) v = *(const f16x8*)(A + (size_t)row * 128 + k0 + q * 8);
            else { f16x8 z = {}; v = z; }
            float4 lo = make_float4((float)v[0], (float)v[1], (float)v[2], (float)v[3]);
            float4 hi = make_float4((float)v[4], (float)v[5], (float)v[6], (float)v[7]);
            As[r][q * 2] = lo;
            As[r][q * 2 + 1] = hi;
        }
#pragma unroll
        for (int i = 0; i < 4; i++) {
            int idx = tid + i * 256;
            int r = idx >> 5, c4 = idx & 31;
            Bs[r][c4] = *(const float4*)(B + (size_t)(k0 + r) * 128 + c4 * 4);
        }
        __syncthreads();

#pragma unroll
        for (int k4 = 0; k4 < 8; k4++) {
            float4 b0 = Bs[k4 * 4 + 0][tx];
            float4 b1 = Bs[k4 * 4 + 1][tx];
            float4 b2 = Bs[k4 * 4 + 2][tx];
            float4 b3 = Bs[k4 * 4 + 3][tx];
#pragma unroll
            for (int i = 0; i < 8; i++) {
                float4 a = As[ty * 8 + i][k4];
                acc[i].x = fmaf(a.x, b0.x, fmaf(a.y, b1.x, fmaf(a.z, b2.x, fmaf(a.w, b3.x, acc[i].x))));
                acc[i].y = fmaf(a.x, b0.y, fmaf(a.y, b1.y, fmaf(a.z, b2.y, fmaf(a.w, b3.y, acc[i].y))));
                acc[i].z = fmaf(a.x, b0.z, fmaf(a.y, b1.z, fmaf(a.z, b2.z, fmaf(a.w, b3.z, acc[i].z))));
                acc[i].w = fmaf(a.x, b0.w, fmaf(a.y, b1.w, fmaf(a.z, b2.w, fmaf(a.w, b3.w, acc[i].w))));
            }
        }
        __syncthreads();
    }

#pragma unroll
    for (int i = 0; i < 8; i++) {
        int row = row0 + ty * 8 + i;
        if (row < M) {
            *(float4*)(C + (size_t)row * 128 + tx * 4) = acc[i];
            bf16x4 c16;
            c16[0] = (__bf16)acc[i].x; c16[1] = (__bf16)acc[i].y;
            c16[2] = (__bf16)acc[i].z; c16[3] = (__bf16)acc[i].w;
            *(bf16x4*)(C16 + (size_t)row * 128 + tx * 4) = c16;
        }
    }
}

// ================= gather-aggregate (bf16 gather, fused finalize, fp16 h out) ====
__global__ __launch_bounds__(THREADS) void k_gather_agg(const int* __restrict__ rowptr,
                                                        const int2* __restrict__ swPair,
                                                        const __bf16* __restrict__ xw16,
                                                        const float* __restrict__ xw,
                                                        const float* __restrict__ dinv,
                                                        const float* __restrict__ bias,
                                                        _Float16* __restrict__ h16, int n) {
    int node = blockIdx.x * 4 + (threadIdx.x >> 6);
    int lane = threadIdx.x & 63;
    int q = lane >> 4;
    int c = lane & 15;          // channels c*8 .. c*8+7
    if (node >= n) return;
    int beg = rowptr[node], end = rowptr[node + 1];
    float di = dinv[node];

    float acc[8];
#pragma unroll
    for (int i = 0; i < 8; i++) acc[i] = 0.f;

    int j = beg;
    for (; j + 15 < end; j += 16) {
        int2 pw0 = swPair[j + q];
        int2 pw1 = swPair[j + 4 + q];
        int2 pw2 = swPair[j + 8 + q];
        int2 pw3 = swPair[j + 12 + q];
        bf16x8 v0 = *(const bf16x8*)(xw16 + (size_t)pw0.x * 128 + c * 8);
        bf16x8 v1 = *(const bf16x8*)(xw16 + (size_t)pw1.x * 128 + c * 8);
        bf16x8 v2 = *(const bf16x8*)(xw16 + (size_t)pw2.x * 128 + c * 8);
        bf16x8 v3 = *(const bf16x8*)(xw16 + (size_t)pw3.x * 128 + c * 8);
        float w0 = __int_as_float(pw0.y);
        float w1 = __int_as_float(pw1.y);
        float w2 = __int_as_float(pw2.y);
        float w3 = __int_as_float(pw3.y);
#pragma unroll
        for (int i = 0; i < 8; i++) {
            acc[i] = fmaf((float)v0[i], w0, acc[i]);
            acc[i] = fmaf((float)v1[i], w1, acc[i]);
            acc[i] = fmaf((float)v2[i], w2, acc[i]);
            acc[i] = fmaf((float)v3[i], w3, acc[i]);
        }
    }
    for (; j + 7 < end; j += 8) {
        int2 pw0 = swPair[j + q];
        int2 pw1 = swPair[j + 4 + q];
        bf16x8 v0 = *(const bf16x8*)(xw16 + (size_t)pw0.x * 128 + c * 8);
        bf16x8 v1 = *(const bf16x8*)(xw16 + (size_t)pw1.x * 128 + c * 8);
        float w0 = __int_as_float(pw0.y);
        float w1 = __int_as_float(pw1.y);
#pragma unroll
        for (int i = 0; i < 8; i++) {
            acc[i] = fmaf((float)v0[i], w0, acc[i]);
            acc[i] = fmaf((float)v1[i], w1, acc[i]);
        }
    }
    for (; j + 3 < end; j += 4) {
        int2 pw = swPair[j + q];
        bf16x8 v = *(const bf16x8*)(xw16 + (size_t)pw.x * 128 + c * 8);
        float w = __int_as_float(pw.y);
#pragma unroll
        for (int i = 0; i < 8; i++) acc[i] = fmaf((float)v[i], w, acc[i]);
    }
    int rem = end - j;
    if (q < rem) {
        int2 pw = swPair[j + q];
        bf16x8 v = *(const bf16x8*)(xw16 + (size_t)pw.x * 128 + c * 8);
        float w = __int_as_float(pw.y);
#pragma unroll
        for (int i = 0; i < 8; i++) acc[i] = fmaf((float)v[i], w, acc[i]);
    }

    // merge quarters
#pragma unroll
    for (int i = 0; i < 8; i++) {
        acc[i] += __shfl_xor(acc[i], 16);
        acc[i] += __shfl_xor(acc[i], 32);
    }

    if (q == 0) {
        float4 xv0 = *(const float4*)(xw + (size_t)node * 128 + c * 8);
        float4 xv1 = *(const float4*)(xw + (size_t)node * 128 + c * 8 + 4);
        float4 b0 = *(const float4*)(bias + c * 8);
        float4 b1 = *(const float4*)(bias + c * 8 + 4);
        float dd = di * di;
        float r[8];
        r[0] = fmaxf(fmaf(acc[0], di, fmaf(xv0.x, dd, b0.x)), 0.f);
        r[1] = fmaxf(fmaf(acc[1], di, fmaf(xv0.y, dd, b0.y)), 0.f);
        r[2] = fmaxf(fmaf(acc[2], di, fmaf(xv0.z, dd, b0.z)), 0.f);
        r[3] = fmaxf(fmaf(acc[3], di, fmaf(xv0.w, dd, b0.w)), 0.f);
        r[4] = fmaxf(fmaf(acc[4], di, fmaf(xv1.x, dd, b1.x)), 0.f);
        r[5] = fmaxf(fmaf(acc[5], di, fmaf(xv1.y, dd, b1.y)), 0.f);
        r[6] = fmaxf(fmaf(acc[6], di, fmaf(xv1.z, dd, b1.z)), 0.f);
        r[7] = fmaxf(fmaf(acc[7], di, fmaf(xv1.w, dd, b1.w)), 0.f);
        f16x8 r16;
#pragma unroll
        for (int i = 0; i < 8; i++) r16[i] = (_Float16)r[i];
        *(f16x8*)(h16 + (size_t)node * 128 + c * 8) = r16;
    }
}

// ================= B-pack: fc1w [256][128] f32 -> MFMA B-fragments fp16 =================
__global__ __launch_bounds__(THREADS) void k_pack_b(const float* __restrict__ fc1w,
                                                    _Float16* __restrict__ bpack) {
    int t = blockIdx.x * THREADS + threadIdx.x;   // 0..4095
    int lane = t & 63;
    int fi = t >> 6;          // ks*8+nt
    int nt = fi & 7, ks = fi >> 3;
    int krow = ks * 32 + (lane >> 4) * 8;
    int col = nt * 16 + (lane & 15);
    f16x8 v;
#pragma unroll
    for (int i = 0; i < 8; i++) v[i] = (_Float16)fc1w[(size_t)(krow + i) * 128 + col];
    *(f16x8*)(bpack + (size_t)t * 8) = v;
}

// ================= edge head (MFMA fp16, dst-sorted, one-shot; r9 structure) ====
// 4 waves/block, 16 sorted-edges/wave. Bias pre-loaded into the accumulator.
__global__ __launch_bounds__(THREADS) void k_edge_head_mfma(const int2* __restrict__ sdSorted,
                                                            const int* __restrict__ edgePerm,
                                                            const _Float16* __restrict__ h16,
                                                            const _Float16* __restrict__ bpack,
                                                            const float* __restrict__ fc1b,
                                                            const float* __restrict__ fc2w,
                                                            const float* __restrict__ fc2b,
                                                            float* __restrict__ out, int E) {
    int tid = threadIdx.x;
    int w = tid >> 6;
    int lane = tid & 63;
    int m = lane & 15;        // A row (edge within wave)
    int kg = lane >> 4;       // k-group: feature = ks*32 + kg*8 + i
    int n0 = lane & 15;
    int rowg = lane >> 4;
    int e0w = blockIdx.x * 64 + w * 16;
    int p = e0w + m;          // sorted position
    bool valid = p < E;
    int2 sd = valid ? sdSorted[p] : make_int2(0, 0);
    const _Float16* px = h16 + (size_t)sd.x * 128 + kg * 8;   // random (256B rows)
    const _Float16* py = h16 + (size_t)sd.y * 128 + kg * 8;   // sorted -> cache-hit

    // issue all loads first (ILP)
    f16x8 xl[4], yl[4];
#pragma unroll
    for (int ks = 0; ks < 4; ks++) {
        xl[ks] = *(const f16x8*)(px + ks * 32);
        yl[ks] = *(const f16x8*)(py + ks * 32);
    }

    // packed fp16 prod/diff -> A fragments
    f16x8 afrag[8];
#pragma unroll
    for (int ks = 0; ks < 4; ks++) {
        afrag[ks]     = xl[ks] * yl[ks];   // v_pk_mul_f16
        afrag[ks + 4] = xl[ks] - yl[ks];   // packed sub
    }

    // acc init = fc1 bias (col-indexed, constant over the 4 row regs)
    f32x4 acc[8];
#pragma unroll
    for (int nt = 0; nt < 8; nt++) {
        float bb = fc1b[nt * 16 + n0];
        acc[nt] = (f32x4){bb, bb, bb, bb};
    }

    const f16x8* bfr = ((const f16x8*)bpack) + lane;
#pragma unroll
    for (int ks = 0; ks < 8; ks++) {
#pragma unroll
        for (int nt = 0; nt < 8; nt++) {
            f16x8 b = bfr[(size_t)(ks * 8 + nt) * 64];
            acc[nt] = __builtin_amdgcn_mfma_f32_16x16x32_f16(afrag[ks], b, acc[nt], 0, 0, 0);
        }
    }

    // epilogue: lane holds cols n = nt*16 + n0, rows m = rowg*4 + r (bias included)
    float partial[4] = {0.f, 0.f, 0.f, 0.f};
#pragma unroll
    for (int nt = 0; nt < 8; nt++) {
        float ww = fc2w[nt * 16 + n0];
#pragma unroll
        for (int r = 0; r < 4; r++) {
            float z = fmaxf(acc[nt][r], 0.f);
            partial[r] = fmaf(z, ww, partial[r]);
        }
    }
#pragma unroll
    for (int r = 0; r < 4; r++) {
        partial[r] += __shfl_xor(partial[r], 1);
        partial[r] += __shfl_xor(partial[r], 2);
        partial[r] += __shfl_xor(partial[r], 4);
        partial[r] += __shfl_xor(partial[r], 8);
    }
    if (n0 == 0) {
        float b2 = fc2b[0];
#pragma unroll
        for (int r = 0; r < 4; r++) {
            int qq = e0w + rowg * 4 + r;
            if (qq < E) out[edgePerm[qq]] = 1.0f / (1.0f + expf(-(partial[r] + b2)));
        }
    }
}

// ================= host =================
extern "C" void kernel_launch(void* const* d_in, const int* in_sizes, int n_in,
                              void* d_out, int out_size, void* d_ws, size_t ws_size,
                              hipStream_t stream) {
    const float* x    = (const float*)d_in[0];
    const int*   ei   = (const int*)d_in[1];
    const float* W1   = (const float*)d_in[2];
    const float* b1   = (const float*)d_in[3];
    const float* W2   = (const float*)d_in[4];
    const float* b2   = (const float*)d_in[5];
    const float* fc1w = (const float*)d_in[6];
    const float* fc1b = (const float*)d_in[7];
    const float* fc2w = (const float*)d_in[8];
    const float* fc2b = (const float*)d_in[9];

    int N = in_sizes[0] / 128;
    int E = in_sizes[1] / 2;
    const int* src = ei;
    const int* dst = ei + E;

    // ---- workspace layout ----
    char* ws = (char*)d_ws;
    size_t off = 0;
    auto alloc = [&](size_t bytes) { char* p = ws + off; off += (bytes + 255) & ~(size_t)255; return p; };
    int*      cnt       = (int*)     alloc((size_t)N * 4);
    int*      rowptr    = (int*)     alloc(((size_t)N + 1) * 4);
    int*      cursor    = (int*)     alloc((size_t)N * 4);
    int*      blockSums = (int*)     alloc(256 * 4);
    int2*     swPair    = (int2*)    alloc((size_t)E * 8);
    int2*     sdSorted  = (int2*)    alloc((size_t)E * 8);
    int*      edgePerm  = (int*)     alloc((size_t)E * 4);
    float*    dinv      = (float*)   alloc((size_t)N * 4);
    _Float16* bpack     = (_Float16*)alloc((size_t)4096 * 8 * 2);     // 64 KB
    float*    xw        = (float*)   alloc((size_t)N * 128 * 4);
    __bf16*   xw16      = (__bf16*)  alloc((size_t)N * 128 * 2);
    _Float16* h16       = (_Float16*)alloc((size_t)N * 128 * 2);

    int gN     = (N + THREADS - 1) / THREADS;
    int gE     = (E + THREADS - 1) / THREADS;
    int nchunk = (N + 1023) / 1024;
    int gGemm  = (N + 63) / 64;
    int gGath  = (N + 3) / 4;
    int gHead  = (E + 63) / 64;

    // ---- CSR build + degrees + B-pack ----
    hipMemsetAsync(cnt, 0, (size_t)N * 4, stream);
    k_hist<<<gE, THREADS, 0, stream>>>(dst, cnt, E);
    k_dinv<<<gN, THREADS, 0, stream>>>(cnt, dinv, N);
    k_scan1<<<nchunk, THREADS, 0, stream>>>(cnt, rowptr, blockSums, N);
    k_scan2<<<1, THREADS, 0, stream>>>(blockSums, rowptr, nchunk, N, E);
    k_scan3<<<gN, THREADS, 0, stream>>>(rowptr, blockSums, N);
    hipMemsetAsync(cursor, 0, (size_t)N * 4, stream);
    k_scatter<<<gE, THREADS, 0, stream>>>(src, dst, rowptr, dinv, cursor,
                                          swPair, sdSorted, edgePerm, E);
    k_pack_b<<<16, THREADS, 0, stream>>>(fc1w, bpack);

    // ---- layer 1 ----
    k_gemm128_f32<<<gGemm, THREADS, 0, stream>>>(x, W1, xw, xw16, N);
    k_gather_agg<<<gGath, THREADS, 0, stream>>>(rowptr, swPair, xw16, xw, dinv, b1, h16, N);

    // ---- layer 2 ----
    k_gemm128_f16<<<gGemm, THREADS, 0, stream>>>(h16, W2, xw, xw16, N);
    k_gather_agg<<<gGath, THREADS, 0, stream>>>(rowptr, swPair, xw16, xw, dinv, b2, h16, N);

    // ---- edge head (MFMA fp16, sorted order) ----
    k_edge_head_mfma<<<gHead, THREADS, 0, stream>>>(sdSorted, edgePerm,
                                                    h16, bpack, fc1b, fc2w, fc2b,
                                                    (float*)d_out, E);
}

// Round 12
// 627.483 us; speedup vs baseline: 1.1062x; 1.0331x over previous
//
#include <hip/hip_runtime.h>

#define THREADS 256

typedef __bf16    bf16x8 __attribute__((ext_vector_type(8)));
typedef __bf16    bf16x4 __attribute__((ext_vector_type(4)));
typedef _Float16  f16x8  __attribute__((ext_vector_type(8)));
typedef float     f32x4  __attribute__((ext_vector_type(4)));

// ================= CSR build: histogram -> scan -> scatter =================

__global__ __launch_bounds__(THREADS) void k_hist(const int* __restrict__ dst,
                                                  int* __restrict__ cnt, int E) {
    int e = blockIdx.x * THREADS + threadIdx.x;
    if (e < E) atomicAdd(&cnt[dst[e]], 1);
}

__global__ __launch_bounds__(THREADS) void k_dinv(const int* __restrict__ cnt,
                                                  float* __restrict__ dinv, int n) {
    int i = blockIdx.x * THREADS + threadIdx.x;
    if (i < n) dinv[i] = rsqrtf((float)cnt[i] + 1.0f);
}

__global__ __launch_bounds__(THREADS) void k_scan1(const int* __restrict__ cnt,
                                                   int* __restrict__ rowptr,
                                                   int* __restrict__ blockSums, int n) {
    __shared__ int part[THREADS];
    int tid = threadIdx.x;
    int base = blockIdx.x * 1024 + tid * 4;
    int v0 = (base + 0 < n) ? cnt[base + 0] : 0;
    int v1 = (base + 1 < n) ? cnt[base + 1] : 0;
    int v2 = (base + 2 < n) ? cnt[base + 2] : 0;
    int v3 = (base + 3 < n) ? cnt[base + 3] : 0;
    part[tid] = v0 + v1 + v2 + v3;
    __syncthreads();
    for (int off = 1; off < THREADS; off <<= 1) {
        int t = 0;
        if (tid >= off) t = part[tid - off];
        __syncthreads();
        if (tid >= off) part[tid] += t;
        __syncthreads();
    }
    int excl = (tid == 0) ? 0 : part[tid - 1];
    if (tid == THREADS - 1) blockSums[blockIdx.x] = part[THREADS - 1];
    int run = excl;
    if (base + 0 < n) rowptr[base + 0] = run; run += v0;
    if (base + 1 < n) rowptr[base + 1] = run; run += v1;
    if (base + 2 < n) rowptr[base + 2] = run; run += v2;
    if (base + 3 < n) rowptr[base + 3] = run;
}

__global__ __launch_bounds__(THREADS) void k_scan2(int* __restrict__ blockSums,
                                                   int* __restrict__ rowptr,
                                                   int nchunks, int n, int E) {
    __shared__ int part[THREADS];
    int tid = threadIdx.x;
    int v = (tid < nchunks) ? blockSums[tid] : 0;
    part[tid] = v;
    __syncthreads();
    for (int off = 1; off < THREADS; off <<= 1) {
        int t = 0;
        if (tid >= off) t = part[tid - off];
        __syncthreads();
        if (tid >= off) part[tid] += t;
        __syncthreads();
    }
    int excl = (tid == 0) ? 0 : part[tid - 1];
    if (tid < nchunks) blockSums[tid] = excl;
    if (tid == 0) rowptr[n] = E;
}

__global__ __launch_bounds__(THREADS) void k_scan3(int* __restrict__ rowptr,
                                                   const int* __restrict__ blockSums, int n) {
    int i = blockIdx.x * THREADS + threadIdx.x;
    if (i < n) rowptr[i] += blockSums[i >> 10];
}

// writes: swPair {src, dinv[src]}, sdSorted {src,dst}, edgePerm
__global__ __launch_bounds__(THREADS) void k_scatter(const int* __restrict__ src,
                                                     const int* __restrict__ dst,
                                                     const int* __restrict__ rowptr,
                                                     const float* __restrict__ dinv,
                                                     int* __restrict__ cursor,
                                                     int2* __restrict__ swPair,
                                                     int2* __restrict__ sdSorted,
                                                     int* __restrict__ edgePerm, int E) {
    int e = blockIdx.x * THREADS + threadIdx.x;
    if (e >= E) return;
    int d = dst[e];
    int s = src[e];
    int pos = rowptr[d] + atomicAdd(&cursor[d], 1);
    swPair[pos] = make_int2(s, __float_as_int(dinv[s]));
    sdSorted[pos] = make_int2(s, d);
    edgePerm[pos] = e;
}

// ================= GEMM (f32 A): C[M][128] = A[M][128] @ B[128][128] ============
__global__ __launch_bounds__(THREADS) void k_gemm128_f32(const float* __restrict__ A,
                                                         const float* __restrict__ B,
                                                         float* __restrict__ C,
                                                         __bf16* __restrict__ C16, int M) {
    __shared__ float4 As[64][8];
    __shared__ float4 Bs[32][32];

    int tid = threadIdx.x;
    int tx = tid & 31;
    int ty = tid >> 5;
    int row0 = blockIdx.x * 64;

    float4 acc[8];
#pragma unroll
    for (int i = 0; i < 8; i++) acc[i] = make_float4(0.f, 0.f, 0.f, 0.f);

    for (int k0 = 0; k0 < 128; k0 += 32) {
#pragma unroll
        for (int i = 0; i < 2; i++) {
            int idx = tid + i * 256;
            int r = idx >> 3, q = idx & 7;
            int row = row0 + r;
            float4 v = make_float4(0.f, 0.f, 0.f, 0.f);
            if (row < M) v = *(const float4*)(A + (size_t)row * 128 + k0 + q * 4);
            As[r][q] = v;
        }
#pragma unroll
        for (int i = 0; i < 4; i++) {
            int idx = tid + i * 256;
            int r = idx >> 5, c4 = idx & 31;
            Bs[r][c4] = *(const float4*)(B + (size_t)(k0 + r) * 128 + c4 * 4);
        }
        __syncthreads();

#pragma unroll
        for (int k4 = 0; k4 < 8; k4++) {
            float4 b0 = Bs[k4 * 4 + 0][tx];
            float4 b1 = Bs[k4 * 4 + 1][tx];
            float4 b2 = Bs[k4 * 4 + 2][tx];
            float4 b3 = Bs[k4 * 4 + 3][tx];
#pragma unroll
            for (int i = 0; i < 8; i++) {
                float4 a = As[ty * 8 + i][k4];
                acc[i].x = fmaf(a.x, b0.x, fmaf(a.y, b1.x, fmaf(a.z, b2.x, fmaf(a.w, b3.x, acc[i].x))));
                acc[i].y = fmaf(a.x, b0.y, fmaf(a.y, b1.y, fmaf(a.z, b2.y, fmaf(a.w, b3.y, acc[i].y))));
                acc[i].z = fmaf(a.x, b0.z, fmaf(a.y, b1.z, fmaf(a.z, b2.z, fmaf(a.w, b3.z, acc[i].z))));
                acc[i].w = fmaf(a.x, b0.w, fmaf(a.y, b1.w, fmaf(a.z, b2.w, fmaf(a.w, b3.w, acc[i].w))));
            }
        }
        __syncthreads();
    }

#pragma unroll
    for (int i = 0; i < 8; i++) {
        int row = row0 + ty * 8 + i;
        if (row < M) {
            *(float4*)(C + (size_t)row * 128 + tx * 4) = acc[i];
            bf16x4 c16;
            c16[0] = (__bf16)acc[i].x; c16[1] = (__bf16)acc[i].y;
            c16[2] = (__bf16)acc[i].z; c16[3] = (__bf16)acc[i].w;
            *(bf16x4*)(C16 + (size_t)row * 128 + tx * 4) = c16;
        }
    }
}

// ================= GEMM (fp16 A): same, A staged from h16 with convert =========
__global__ __launch_bounds__(THREADS) void k_gemm128_f16(const _Float16* __restrict__ A,
                                                         const float* __restrict__ B,
                                                         float* __restrict__ C,
                                                         __bf16* __restrict__ C16, int M) {
    __shared__ float4 As[64][8];
    __shared__ float4 Bs[32][32];

    int tid = threadIdx.x;
    int tx = tid & 31;
    int ty = tid >> 5;
    int row0 = blockIdx.x * 64;

    float4 acc[8];
#pragma unroll
    for (int i = 0; i < 8; i++) acc[i] = make_float4(0.f, 0.f, 0.f, 0.f);

    for (int k0 = 0; k0 < 128; k0 += 32) {
        {
            int r = tid >> 2, q = tid & 3;
            int row = row0 + r;
            f16x8 v;
            if (row < M) v = *(const f16x8*)(A + (size_t)row * 128 + k0 + q * 8);
            else { f16x8 z = {}; v = z; }
            float4 lo = make_float4((float)v[0], (float)v[1], (float)v[2], (float)v[3]);
            float4 hi = make_float4((float)v[4], (float)v[5], (float)v[6], (float)v[7]);
            As[r][q * 2] = lo;
            As[r][q * 2 + 1] = hi;
        }
#pragma unroll
        for (int i = 0; i < 4; i++) {
            int idx = tid + i * 256;
            int r = idx >> 5, c4 = idx & 31;
            Bs[r][c4] = *(const float4*)(B + (size_t)(k0 + r) * 128 + c4 * 4);
        }
        __syncthreads();

#pragma unroll
        for (int k4 = 0; k4 < 8; k4++) {
            float4 b0 = Bs[k4 * 4 + 0][tx];
            float4 b1 = Bs[k4 * 4 + 1][tx];
            float4 b2 = Bs[k4 * 4 + 2][tx];
            float4 b3 = Bs[k4 * 4 + 3][tx];
#pragma unroll
            for (int i = 0; i < 8; i++) {
                float4 a = As[ty * 8 + i][k4];
                acc[i].x = fmaf(a.x, b0.x, fmaf(a.y, b1.x, fmaf(a.z, b2.x, fmaf(a.w, b3.x, acc[i].x))));
                acc[i].y = fmaf(a.x, b0.y, fmaf(a.y, b1.y, fmaf(a.z, b2.y, fmaf(a.w, b3.y, acc[i].y))));
                acc[i].z = fmaf(a.x, b0.z, fmaf(a.y, b1.z, fmaf(a.z, b2.z, fmaf(a.w, b3.z, acc[i].z))));
                acc[i].w = fmaf(a.x, b0.w, fmaf(a.y, b1.w, fmaf(a.z, b2.w, fmaf(a.w, b3.w, acc[i].w))));
            }
        }
        __syncthreads();
    }

#pragma unroll
    for (int i = 0; i < 8; i++) {
        int row = row0 + ty * 8 + i;
        if (row < M) {
            *(float4*)(C + (size_t)row * 128 + tx * 4) = acc[i];
            bf16x4 c16;
            c16[0] = (__bf16)acc[i].x; c16[1] = (__bf16)acc[i].y;
            c16[2] = (__bf16)acc[i].z; c16[3] = (__bf16)acc[i].w;
            *(bf16x4*)(C16 + (size_t)row * 128 + tx * 4) = c16;
        }
    }
}

// ================= gather-aggregate (bf16 gather, fused finalize, fp16 h out) ====
__global__ __launch_bounds__(THREADS) void k_gather_agg(const int* __restrict__ rowptr,
                                                        const int2* __restrict__ swPair,
                                                        const __bf16* __restrict__ xw16,
                                                        const float* __restrict__ xw,
                                                        const float* __restrict__ dinv,
                                                        const float* __restrict__ bias,
                                                        _Float16* __restrict__ h16, int n) {
    int node = blockIdx.x * 4 + (threadIdx.x >> 6);
    int lane = threadIdx.x & 63;
    int q = lane >> 4;
    int c = lane & 15;          // channels c*8 .. c*8+7
    if (node >= n) return;
    int beg = rowptr[node], end = rowptr[node + 1];
    float di = dinv[node];

    float acc[8];
#pragma unroll
    for (int i = 0; i < 8; i++) acc[i] = 0.f;

    int j = beg;
    for (; j + 15 < end; j += 16) {
        int2 pw0 = swPair[j + q];
        int2 pw1 = swPair[j + 4 + q];
        int2 pw2 = swPair[j + 8 + q];
        int2 pw3 = swPair[j + 12 + q];
        bf16x8 v0 = *(const bf16x8*)(xw16 + (size_t)pw0.x * 128 + c * 8);
        bf16x8 v1 = *(const bf16x8*)(xw16 + (size_t)pw1.x * 128 + c * 8);
        bf16x8 v2 = *(const bf16x8*)(xw16 + (size_t)pw2.x * 128 + c * 8);
        bf16x8 v3 = *(const bf16x8*)(xw16 + (size_t)pw3.x * 128 + c * 8);
        float w0 = __int_as_float(pw0.y);
        float w1 = __int_as_float(pw1.y);
        float w2 = __int_as_float(pw2.y);
        float w3 = __int_as_float(pw3.y);
#pragma unroll
        for (int i = 0; i < 8; i++) {
            acc[i] = fmaf((float)v0[i], w0, acc[i]);
            acc[i] = fmaf((float)v1[i], w1, acc[i]);
            acc[i] = fmaf((float)v2[i], w2, acc[i]);
            acc[i] = fmaf((float)v3[i], w3, acc[i]);
        }
    }
    for (; j + 7 < end; j += 8) {
        int2 pw0 = swPair[j + q];
        int2 pw1 = swPair[j + 4 + q];
        bf16x8 v0 = *(const bf16x8*)(xw16 + (size_t)pw0.x * 128 + c * 8);
        bf16x8 v1 = *(const bf16x8*)(xw16 + (size_t)pw1.x * 128 + c * 8);
        float w0 = __int_as_float(pw0.y);
        float w1 = __int_as_float(pw1.y);
#pragma unroll
        for (int i = 0; i < 8; i++) {
            acc[i] = fmaf((float)v0[i], w0, acc[i]);
            acc[i] = fmaf((float)v1[i], w1, acc[i]);
        }
    }
    for (; j + 3 < end; j += 4) {
        int2 pw = swPair[j + q];
        bf16x8 v = *(const bf16x8*)(xw16 + (size_t)pw.x * 128 + c * 8);
        float w = __int_as_float(pw.y);
#pragma unroll
        for (int i = 0; i < 8; i++) acc[i] = fmaf((float)v[i], w, acc[i]);
    }
    int rem = end - j;
    if (q < rem) {
        int2 pw = swPair[j + q];
        bf16x8 v = *(const bf16x8*)(xw16 + (size_t)pw.x * 128 + c * 8);
        float w = __int_as_float(pw.y);
#pragma unroll
        for (int i = 0; i < 8; i++) acc[i] = fmaf((float)v[i], w, acc[i]);
    }

    // merge quarters
#pragma unroll
    for (int i = 0; i < 8; i++) {
        acc[i] += __shfl_xor(acc[i], 16);
        acc[i] += __shfl_xor(acc[i], 32);
    }

    if (q == 0) {
        float4 xv0 = *(const float4*)(xw + (size_t)node * 128 + c * 8);
        float4 xv1 = *(const float4*)(xw + (size_t)node * 128 + c * 8 + 4);
        float4 b0 = *(const float4*)(bias + c * 8);
        float4 b1 = *(const float4*)(bias + c * 8 + 4);
        float dd = di * di;
        float r[8];
        r[0] = fmaxf(fmaf(acc[0], di, fmaf(xv0.x, dd, b0.x)), 0.f);
        r[1] = fmaxf(fmaf(acc[1], di, fmaf(xv0.y, dd, b0.y)), 0.f);
        r[2] = fmaxf(fmaf(acc[2], di, fmaf(xv0.z, dd, b0.z)), 0.f);
        r[3] = fmaxf(fmaf(acc[3], di, fmaf(xv0.w, dd, b0.w)), 0.f);
        r[4] = fmaxf(fmaf(acc[4], di, fmaf(xv1.x, dd, b1.x)), 0.f);
        r[5] = fmaxf(fmaf(acc[5], di, fmaf(xv1.y, dd, b1.y)), 0.f);
        r[6] = fmaxf(fmaf(acc[6], di, fmaf(xv1.z, dd, b1.z)), 0.f);
        r[7] = fmaxf(fmaf(acc[7], di, fmaf(xv1.w, dd, b1.w)), 0.f);
        f16x8 r16;
#pragma unroll
        for (int i = 0; i < 8; i++) r16[i] = (_Float16)r[i];
        *(f16x8*)(h16 + (size_t)node * 128 + c * 8) = r16;
    }
}

// ================= B-pack: fc1w [256][128] f32 -> MFMA B-fragments fp16 =================
__global__ __launch_bounds__(THREADS) void k_pack_b(const float* __restrict__ fc1w,
                                                    _Float16* __restrict__ bpack) {
    int t = blockIdx.x * THREADS + threadIdx.x;   // 0..4095
    int lane = t & 63;
    int fi = t >> 6;          // ks*8+nt
    int nt = fi & 7, ks = fi >> 3;
    int krow = ks * 32 + (lane >> 4) * 8;
    int col = nt * 16 + (lane & 15);
    f16x8 v;
#pragma unroll
    for (int i = 0; i < 8; i++) v[i] = (_Float16)fc1w[(size_t)(krow + i) * 128 + col];
    *(f16x8*)(bpack + (size_t)t * 8) = v;
}

// ================= edge head (MFMA fp16, dst-sorted, LDS-staged B) ==============
// 4 waves/block, 16 sorted-edges/wave (r11 structure). fc1w B-fragments staged
// once per block into 64KB LDS -> B reads leave the vL1 path (which was the
// binding line-throughput constraint) and use the LDS pipe instead.
__global__ __launch_bounds__(THREADS) void k_edge_head_mfma(const int2* __restrict__ sdSorted,
                                                            const int* __restrict__ edgePerm,
                                                            const _Float16* __restrict__ h16,
                                                            const _Float16* __restrict__ bpack,
                                                            const float* __restrict__ fc1b,
                                                            const float* __restrict__ fc2w,
                                                            const float* __restrict__ fc2b,
                                                            float* __restrict__ out, int E) {
    __shared__ _Float16 bsh[4096 * 8];   // 64 KB

    int tid = threadIdx.x;
    // cooperative stage: 4096 x 16B, coalesced
    {
        const int4* gsrc = (const int4*)bpack;
        int4* ldst = (int4*)bsh;
#pragma unroll
        for (int i = 0; i < 16; i++) ldst[tid + i * 256] = gsrc[tid + i * 256];
    }

    int w = tid >> 6;
    int lane = tid & 63;
    int m = lane & 15;        // A row (edge within wave)
    int kg = lane >> 4;       // k-group: feature = ks*32 + kg*8 + i
    int n0 = lane & 15;
    int rowg = lane >> 4;
    int e0w = blockIdx.x * 64 + w * 16;
    int p = e0w + m;          // sorted position
    bool valid = p < E;
    int2 sd = valid ? sdSorted[p] : make_int2(0, 0);
    const _Float16* px = h16 + (size_t)sd.x * 128 + kg * 8;   // random (256B rows)
    const _Float16* py = h16 + (size_t)sd.y * 128 + kg * 8;   // sorted -> cache-hit

    // issue all gathers (overlap with LDS stage completing)
    f16x8 xl[4], yl[4];
#pragma unroll
    for (int ks = 0; ks < 4; ks++) {
        xl[ks] = *(const f16x8*)(px + ks * 32);
        yl[ks] = *(const f16x8*)(py + ks * 32);
    }

    // packed fp16 prod/diff -> A fragments
    f16x8 afrag[8];
#pragma unroll
    for (int ks = 0; ks < 4; ks++) {
        afrag[ks]     = xl[ks] * yl[ks];   // v_pk_mul_f16
        afrag[ks + 4] = xl[ks] - yl[ks];   // packed sub
    }

    // acc init = fc1 bias (col-indexed, constant over the 4 row regs)
    f32x4 acc[8];
#pragma unroll
    for (int nt = 0; nt < 8; nt++) {
        float bb = fc1b[nt * 16 + n0];
        acc[nt] = (f32x4){bb, bb, bb, bb};
    }

    __syncthreads();   // bsh ready

    const f16x8* bfr = ((const f16x8*)bsh) + lane;
#pragma unroll
    for (int ks = 0; ks < 8; ks++) {
#pragma unroll
        for (int nt = 0; nt < 8; nt++) {
            f16x8 b = bfr[(ks * 8 + nt) * 64];
            acc[nt] = __builtin_amdgcn_mfma_f32_16x16x32_f16(afrag[ks], b, acc[nt], 0, 0, 0);
        }
    }

    // epilogue: lane holds cols n = nt*16 + n0, rows m = rowg*4 + r (bias included)
    float partial[4] = {0.f, 0.f, 0.f, 0.f};
#pragma unroll
    for (int nt = 0; nt < 8; nt++) {
        float ww = fc2w[nt * 16 + n0];
#pragma unroll
        for (int r = 0; r < 4; r++) {
            float z = fmaxf(acc[nt][r], 0.f);
            partial[r] = fmaf(z, ww, partial[r]);
        }
    }
#pragma unroll
    for (int r = 0; r < 4; r++) {
        partial[r] += __shfl_xor(partial[r], 1);
        partial[r] += __shfl_xor(partial[r], 2);
        partial[r] += __shfl_xor(partial[r], 4);
        partial[r] += __shfl_xor(partial[r], 8);
    }
    if (n0 == 0) {
        float b2 = fc2b[0];
#pragma unroll
        for (int r = 0; r < 4; r++) {
            int qq = e0w + rowg * 4 + r;
            if (qq < E) out[edgePerm[qq]] = 1.0f / (1.0f + expf(-(partial[r] + b2)));
        }
    }
}

// ================= host =================
extern "C" void kernel_launch(void* const* d_in, const int* in_sizes, int n_in,
                              void* d_out, int out_size, void* d_ws, size_t ws_size,
                              hipStream_t stream) {
    const float* x    = (const float*)d_in[0];
    const int*   ei   = (const int*)d_in[1];
    const float* W1   = (const float*)d_in[2];
    const float* b1   = (const float*)d_in[3];
    const float* W2   = (const float*)d_in[4];
    const float* b2   = (const float*)d_in[5];
    const float* fc1w = (const float*)d_in[6];
    const float* fc1b = (const float*)d_in[7];
    const float* fc2w = (const float*)d_in[8];
    const float* fc2b = (const float*)d_in[9];

    int N = in_sizes[0] / 128;
    int E = in_sizes[1] / 2;
    const int* src = ei;
    const int* dst = ei + E;

    // ---- workspace layout ----
    char* ws = (char*)d_ws;
    size_t off = 0;
    auto alloc = [&](size_t bytes) { char* p = ws + off; off += (bytes + 255) & ~(size_t)255; return p; };
    int*      cnt       = (int*)     alloc((size_t)N * 4);
    int*      rowptr    = (int*)     alloc(((size_t)N + 1) * 4);
    int*      cursor    = (int*)     alloc((size_t)N * 4);
    int*      blockSums = (int*)     alloc(256 * 4);
    int2*     swPair    = (int2*)    alloc((size_t)E * 8);
    int2*     sdSorted  = (int2*)    alloc((size_t)E * 8);
    int*      edgePerm  = (int*)     alloc((size_t)E * 4);
    float*    dinv      = (float*)   alloc((size_t)N * 4);
    _Float16* bpack     = (_Float16*)alloc((size_t)4096 * 8 * 2);     // 64 KB
    float*    xw        = (float*)   alloc((size_t)N * 128 * 4);
    __bf16*   xw16      = (__bf16*)  alloc((size_t)N * 128 * 2);
    _Float16* h16       = (_Float16*)alloc((size_t)N * 128 * 2);

    int gN     = (N + THREADS - 1) / THREADS;
    int gE     = (E + THREADS - 1) / THREADS;
    int nchunk = (N + 1023) / 1024;
    int gGemm  = (N + 63) / 64;
    int gGath  = (N + 3) / 4;
    int gHead  = (E + 63) / 64;

    // ---- CSR build + degrees + B-pack ----
    hipMemsetAsync(cnt, 0, (size_t)N * 4, stream);
    k_hist<<<gE, THREADS, 0, stream>>>(dst, cnt, E);
    k_dinv<<<gN, THREADS, 0, stream>>>(cnt, dinv, N);
    k_scan1<<<nchunk, THREADS, 0, stream>>>(cnt, rowptr, blockSums, N);
    k_scan2<<<1, THREADS, 0, stream>>>(blockSums, rowptr, nchunk, N, E);
    k_scan3<<<gN, THREADS, 0, stream>>>(rowptr, blockSums, N);
    hipMemsetAsync(cursor, 0, (size_t)N * 4, stream);
    k_scatter<<<gE, THREADS, 0, stream>>>(src, dst, rowptr, dinv, cursor,
                                          swPair, sdSorted, edgePerm, E);
    k_pack_b<<<16, THREADS, 0, stream>>>(fc1w, bpack);

    // ---- layer 1 ----
    k_gemm128_f32<<<gGemm, THREADS, 0, stream>>>(x, W1, xw, xw16, N);
    k_gather_agg<<<gGath, THREADS, 0, stream>>>(rowptr, swPair, xw16, xw, dinv, b1, h16, N);

    // ---- layer 2 ----
    k_gemm128_f16<<<gGemm, THREADS, 0, stream>>>(h16, W2, xw, xw16, N);
    k_gather_agg<<<gGath, THREADS, 0, stream>>>(rowptr, swPair, xw16, xw, dinv, b2, h16, N);

    // ---- edge head (MFMA fp16, sorted order, LDS-staged B) ----
    k_edge_head_mfma<<<gHead, THREADS, 0, stream>>>(sdSorted, edgePerm,
                                                    h16, bpack, fc1b, fc2w, fc2b,
                                                    (float*)d_out, E);
}

// Round 13
// 560.818 us; speedup vs baseline: 1.2377x; 1.1189x over previous
//
#include <hip/hip_runtime.h>

#define THREADS 256

typedef __bf16    bf16x8 __attribute__((ext_vector_type(8)));
typedef __bf16    bf16x4 __attribute__((ext_vector_type(4)));
typedef _Float16  f16x8  __attribute__((ext_vector_type(8)));
typedef float     f32x4  __attribute__((ext_vector_type(4)));

// ================= CSR build: histogram -> scan -> scatter =================

__global__ __launch_bounds__(THREADS) void k_hist(const int* __restrict__ dst,
                                                  int* __restrict__ cnt, int E) {
    int e = blockIdx.x * THREADS + threadIdx.x;
    if (e < E) atomicAdd(&cnt[dst[e]], 1);
}

__global__ __launch_bounds__(THREADS) void k_dinv(const int* __restrict__ cnt,
                                                  float* __restrict__ dinv, int n) {
    int i = blockIdx.x * THREADS + threadIdx.x;
    if (i < n) dinv[i] = rsqrtf((float)cnt[i] + 1.0f);
}

__global__ __launch_bounds__(THREADS) void k_scan1(const int* __restrict__ cnt,
                                                   int* __restrict__ rowptr,
                                                   int* __restrict__ blockSums, int n) {
    __shared__ int part[THREADS];
    int tid = threadIdx.x;
    int base = blockIdx.x * 1024 + tid * 4;
    int v0 = (base + 0 < n) ? cnt[base + 0] : 0;
    int v1 = (base + 1 < n) ? cnt[base + 1] : 0;
    int v2 = (base + 2 < n) ? cnt[base + 2] : 0;
    int v3 = (base + 3 < n) ? cnt[base + 3] : 0;
    part[tid] = v0 + v1 + v2 + v3;
    __syncthreads();
    for (int off = 1; off < THREADS; off <<= 1) {
        int t = 0;
        if (tid >= off) t = part[tid - off];
        __syncthreads();
        if (tid >= off) part[tid] += t;
        __syncthreads();
    }
    int excl = (tid == 0) ? 0 : part[tid - 1];
    if (tid == THREADS - 1) blockSums[blockIdx.x] = part[THREADS - 1];
    int run = excl;
    if (base + 0 < n) rowptr[base + 0] = run; run += v0;
    if (base + 1 < n) rowptr[base + 1] = run; run += v1;
    if (base + 2 < n) rowptr[base + 2] = run; run += v2;
    if (base + 3 < n) rowptr[base + 3] = run;
}

__global__ __launch_bounds__(THREADS) void k_scan2(int* __restrict__ blockSums,
                                                   int* __restrict__ rowptr,
                                                   int nchunks, int n, int E) {
    __shared__ int part[THREADS];
    int tid = threadIdx.x;
    int v = (tid < nchunks) ? blockSums[tid] : 0;
    part[tid] = v;
    __syncthreads();
    for (int off = 1; off < THREADS; off <<= 1) {
        int t = 0;
        if (tid >= off) t = part[tid - off];
        __syncthreads();
        if (tid >= off) part[tid] += t;
        __syncthreads();
    }
    int excl = (tid == 0) ? 0 : part[tid - 1];
    if (tid < nchunks) blockSums[tid] = excl;
    if (tid == 0) rowptr[n] = E;
}

__global__ __launch_bounds__(THREADS) void k_scan3(int* __restrict__ rowptr,
                                                   const int* __restrict__ blockSums, int n) {
    int i = blockIdx.x * THREADS + threadIdx.x;
    if (i < n) rowptr[i] += blockSums[i >> 10];
}

// writes: swPair {src, dinv[src]}, sdSorted {src,dst}, edgePerm
__global__ __launch_bounds__(THREADS) void k_scatter(const int* __restrict__ src,
                                                     const int* __restrict__ dst,
                                                     const int* __restrict__ rowptr,
                                                     const float* __restrict__ dinv,
                                                     int* __restrict__ cursor,
                                                     int2* __restrict__ swPair,
                                                     int2* __restrict__ sdSorted,
                                                     int* __restrict__ edgePerm, int E) {
    int e = blockIdx.x * THREADS + threadIdx.x;
    if (e >= E) return;
    int d = dst[e];
    int s = src[e];
    int pos = rowptr[d] + atomicAdd(&cursor[d], 1);
    swPair[pos] = make_int2(s, __float_as_int(dinv[s]));
    sdSorted[pos] = make_int2(s, d);
    edgePerm[pos] = e;
}

// ================= GEMM (f32 A): C[M][128] = A[M][128] @ B[128][128] ============
__global__ __launch_bounds__(THREADS) void k_gemm128_f32(const float* __restrict__ A,
                                                         const float* __restrict__ B,
                                                         float* __restrict__ C,
                                                         __bf16* __restrict__ C16, int M) {
    __shared__ float4 As[64][8];
    __shared__ float4 Bs[32][32];

    int tid = threadIdx.x;
    int tx = tid & 31;
    int ty = tid >> 5;
    int row0 = blockIdx.x * 64;

    float4 acc[8];
#pragma unroll
    for (int i = 0; i < 8; i++) acc[i] = make_float4(0.f, 0.f, 0.f, 0.f);

    for (int k0 = 0; k0 < 128; k0 += 32) {
#pragma unroll
        for (int i = 0; i < 2; i++) {
            int idx = tid + i * 256;
            int r = idx >> 3, q = idx & 7;
            int row = row0 + r;
            float4 v = make_float4(0.f, 0.f, 0.f, 0.f);
            if (row < M) v = *(const float4*)(A + (size_t)row * 128 + k0 + q * 4);
            As[r][q] = v;
        }
#pragma unroll
        for (int i = 0; i < 4; i++) {
            int idx = tid + i * 256;
            int r = idx >> 5, c4 = idx & 31;
            Bs[r][c4] = *(const float4*)(B + (size_t)(k0 + r) * 128 + c4 * 4);
        }
        __syncthreads();

#pragma unroll
        for (int k4 = 0; k4 < 8; k4++) {
            float4 b0 = Bs[k4 * 4 + 0][tx];
            float4 b1 = Bs[k4 * 4 + 1][tx];
            float4 b2 = Bs[k4 * 4 + 2][tx];
            float4 b3 = Bs[k4 * 4 + 3][tx];
#pragma unroll
            for (int i = 0; i < 8; i++) {
                float4 a = As[ty * 8 + i][k4];
                acc[i].x = fmaf(a.x, b0.x, fmaf(a.y, b1.x, fmaf(a.z, b2.x, fmaf(a.w, b3.x, acc[i].x))));
                acc[i].y = fmaf(a.x, b0.y, fmaf(a.y, b1.y, fmaf(a.z, b2.y, fmaf(a.w, b3.y, acc[i].y))));
                acc[i].z = fmaf(a.x, b0.z, fmaf(a.y, b1.z, fmaf(a.z, b2.z, fmaf(a.w, b3.z, acc[i].z))));
                acc[i].w = fmaf(a.x, b0.w, fmaf(a.y, b1.w, fmaf(a.z, b2.w, fmaf(a.w, b3.w, acc[i].w))));
            }
        }
        __syncthreads();
    }

#pragma unroll
    for (int i = 0; i < 8; i++) {
        int row = row0 + ty * 8 + i;
        if (row < M) {
            *(float4*)(C + (size_t)row * 128 + tx * 4) = acc[i];
            bf16x4 c16;
            c16[0] = (__bf16)acc[i].x; c16[1] = (__bf16)acc[i].y;
            c16[2] = (__bf16)acc[i].z; c16[3] = (__bf16)acc[i].w;
            *(bf16x4*)(C16 + (size_t)row * 128 + tx * 4) = c16;
        }
    }
}

// ================= GEMM (fp16 A): same, A staged from h16 with convert =========
__global__ __launch_bounds__(THREADS) void k_gemm128_f16(const _Float16* __restrict__ A,
                                                         const float* __restrict__ B,
                                                         float* __restrict__ C,
                                                         __bf16* __restrict__ C16, int M) {
    __shared__ float4 As[64][8];
    __shared__ float4 Bs[32][32];

    int tid = threadIdx.x;
    int tx = tid & 31;
    int ty = tid >> 5;
    int row0 = blockIdx.x * 64;

    float4 acc[8];
#pragma unroll
    for (int i = 0; i < 8; i++) acc[i] = make_float4(0.f, 0.f, 0.f, 0.f);

    for (int k0 = 0; k0 < 128; k0 += 32) {
        {
            int r = tid >> 2, q = tid & 3;
            int row = row0 + r;
            f16x8 v;
            if (row < M) v = *(const f16x8*)(A + (size_t)row * 128 + k0 + q * 8);
            else { f16x8 z = {}; v = z; }
            float4 lo = make_float4((float)v[0], (float)v[1], (float)v[2], (float)v[3]);
            float4 hi = make_float4((float)v[4], (float)v[5], (float)v[6], (float)v[7]);
            As[r][q * 2] = lo;
            As[r][q * 2 + 1] = hi;
        }
#pragma unroll
        for (int i = 0; i < 4; i++) {
            int idx = tid + i * 256;
            int r = idx >> 5, c4 = idx & 31;
            Bs[r][c4] = *(const float4*)(B + (size_t)(k0 + r) * 128 + c4 * 4);
        }
        __syncthreads();

#pragma unroll
        for (int k4 = 0; k4 < 8; k4++) {
            float4 b0 = Bs[k4 * 4 + 0][tx];
            float4 b1 = Bs[k4 * 4 + 1][tx];
            float4 b2 = Bs[k4 * 4 + 2][tx];
            float4 b3 = Bs[k4 * 4 + 3][tx];
#pragma unroll
            for (int i = 0; i < 8; i++) {
                float4 a = As[ty * 8 + i][k4];
                acc[i].x = fmaf(a.x, b0.x, fmaf(a.y, b1.x, fmaf(a.z, b2.x, fmaf(a.w, b3.x, acc[i].x))));
                acc[i].y = fmaf(a.x, b0.y, fmaf(a.y, b1.y, fmaf(a.z, b2.y, fmaf(a.w, b3.y, acc[i].y))));
                acc[i].z = fmaf(a.x, b0.z, fmaf(a.y, b1.z, fmaf(a.z, b2.z, fmaf(a.w, b3.z, acc[i].z))));
                acc[i].w = fmaf(a.x, b0.w, fmaf(a.y, b1.w, fmaf(a.z, b2.w, fmaf(a.w, b3.w, acc[i].w))));
            }
        }
        __syncthreads();
    }

#pragma unroll
    for (int i = 0; i < 8; i++) {
        int row = row0 + ty * 8 + i;
        if (row < M) {
            *(float4*)(C + (size_t)row * 128 + tx * 4) = acc[i];
            bf16x4 c16;
            c16[0] = (__bf16)acc[i].x; c16[1] = (__bf16)acc[i].y;
            c16[2] = (__bf16)acc[i].z; c16[3] = (__bf16)acc[i].w;
            *(bf16x4*)(C16 + (size_t)row * 128 + tx * 4) = c16;
        }
    }
}

// ================= gather-aggregate (bf16 gather, fused finalize, fp16 h out) ====
__global__ __launch_bounds__(THREADS) void k_gather_agg(const int* __restrict__ rowptr,
                                                        const int2* __restrict__ swPair,
                                                        const __bf16* __restrict__ xw16,
                                                        const float* __restrict__ xw,
                                                        const float* __restrict__ dinv,
                                                        const float* __restrict__ bias,
                                                        _Float16* __restrict__ h16, int n) {
    int node = blockIdx.x * 4 + (threadIdx.x >> 6);
    int lane = threadIdx.x & 63;
    int q = lane >> 4;
    int c = lane & 15;          // channels c*8 .. c*8+7
    if (node >= n) return;
    int beg = rowptr[node], end = rowptr[node + 1];
    float di = dinv[node];

    float acc[8];
#pragma unroll
    for (int i = 0; i < 8; i++) acc[i] = 0.f;

    int j = beg;
    for (; j + 15 < end; j += 16) {
        int2 pw0 = swPair[j + q];
        int2 pw1 = swPair[j + 4 + q];
        int2 pw2 = swPair[j + 8 + q];
        int2 pw3 = swPair[j + 12 + q];
        bf16x8 v0 = *(const bf16x8*)(xw16 + (size_t)pw0.x * 128 + c * 8);
        bf16x8 v1 = *(const bf16x8*)(xw16 + (size_t)pw1.x * 128 + c * 8);
        bf16x8 v2 = *(const bf16x8*)(xw16 + (size_t)pw2.x * 128 + c * 8);
        bf16x8 v3 = *(const bf16x8*)(xw16 + (size_t)pw3.x * 128 + c * 8);
        float w0 = __int_as_float(pw0.y);
        float w1 = __int_as_float(pw1.y);
        float w2 = __int_as_float(pw2.y);
        float w3 = __int_as_float(pw3.y);
#pragma unroll
        for (int i = 0; i < 8; i++) {
            acc[i] = fmaf((float)v0[i], w0, acc[i]);
            acc[i] = fmaf((float)v1[i], w1, acc[i]);
            acc[i] = fmaf((float)v2[i], w2, acc[i]);
            acc[i] = fmaf((float)v3[i], w3, acc[i]);
        }
    }
    for (; j + 7 < end; j += 8) {
        int2 pw0 = swPair[j + q];
        int2 pw1 = swPair[j + 4 + q];
        bf16x8 v0 = *(const bf16x8*)(xw16 + (size_t)pw0.x * 128 + c * 8);
        bf16x8 v1 = *(const bf16x8*)(xw16 + (size_t)pw1.x * 128 + c * 8);
        float w0 = __int_as_float(pw0.y);
        float w1 = __int_as_float(pw1.y);
#pragma unroll
        for (int i = 0; i < 8; i++) {
            acc[i] = fmaf((float)v0[i], w0, acc[i]);
            acc[i] = fmaf((float)v1[i], w1, acc[i]);
        }
    }
    for (; j + 3 < end; j += 4) {
        int2 pw = swPair[j + q];
        bf16x8 v = *(const bf16x8*)(xw16 + (size_t)pw.x * 128 + c * 8);
        float w = __int_as_float(pw.y);
#pragma unroll
        for (int i = 0; i < 8; i++) acc[i] = fmaf((float)v[i], w, acc[i]);
    }
    int rem = end - j;
    if (q < rem) {
        int2 pw = swPair[j + q];
        bf16x8 v = *(const bf16x8*)(xw16 + (size_t)pw.x * 128 + c * 8);
        float w = __int_as_float(pw.y);
#pragma unroll
        for (int i = 0; i < 8; i++) acc[i] = fmaf((float)v[i], w, acc[i]);
    }

    // merge quarters
#pragma unroll
    for (int i = 0; i < 8; i++) {
        acc[i] += __shfl_xor(acc[i], 16);
        acc[i] += __shfl_xor(acc[i], 32);
    }

    if (q == 0) {
        float4 xv0 = *(const float4*)(xw + (size_t)node * 128 + c * 8);
        float4 xv1 = *(const float4*)(xw + (size_t)node * 128 + c * 8 + 4);
        float4 b0 = *(const float4*)(bias + c * 8);
        float4 b1 = *(const float4*)(bias + c * 8 + 4);
        float dd = di * di;
        float r[8];
        r[0] = fmaxf(fmaf(acc[0], di, fmaf(xv0.x, dd, b0.x)), 0.f);
        r[1] = fmaxf(fmaf(acc[1], di, fmaf(xv0.y, dd, b0.y)), 0.f);
        r[2] = fmaxf(fmaf(acc[2], di, fmaf(xv0.z, dd, b0.z)), 0.f);
        r[3] = fmaxf(fmaf(acc[3], di, fmaf(xv0.w, dd, b0.w)), 0.f);
        r[4] = fmaxf(fmaf(acc[4], di, fmaf(xv1.x, dd, b1.x)), 0.f);
        r[5] = fmaxf(fmaf(acc[5], di, fmaf(xv1.y, dd, b1.y)), 0.f);
        r[6] = fmaxf(fmaf(acc[6], di, fmaf(xv1.z, dd, b1.z)), 0.f);
        r[7] = fmaxf(fmaf(acc[7], di, fmaf(xv1.w, dd, b1.w)), 0.f);
        f16x8 r16;
#pragma unroll
        for (int i = 0; i < 8; i++) r16[i] = (_Float16)r[i];
        *(f16x8*)(h16 + (size_t)node * 128 + c * 8) = r16;
    }
}

// ================= B-pack: fc1w [256][128] f32 -> MFMA B-fragments fp16 =================
__global__ __launch_bounds__(THREADS) void k_pack_b(const float* __restrict__ fc1w,
                                                    _Float16* __restrict__ bpack) {
    int t = blockIdx.x * THREADS + threadIdx.x;   // 0..4095
    int lane = t & 63;
    int fi = t >> 6;          // ks*8+nt
    int nt = fi & 7, ks = fi >> 3;
    int krow = ks * 32 + (lane >> 4) * 8;
    int col = nt * 16 + (lane & 15);
    f16x8 v;
#pragma unroll
    for (int i = 0; i < 8; i++) v[i] = (_Float16)fc1w[(size_t)(krow + i) * 128 + col];
    *(f16x8*)(bpack + (size_t)t * 8) = v;
}

// ================= edge head (MFMA fp16, LDS B, 4 tiles/wave, dbuf pipeline) ====
// 4 waves/block, 4 consecutive 16-edge tiles per wave (256 edges/block).
// B staged once per block into 64KB LDS (amortized 4x vs r12); next tile's
// gathers issue before current tile's MFMA+epilogue. Occupancy is LDS-bound
// (2 blocks/CU), so the extra pipeline registers are free.
__global__ __launch_bounds__(THREADS) void k_edge_head_mfma(const int2* __restrict__ sdSorted,
                                                            const int* __restrict__ edgePerm,
                                                            const _Float16* __restrict__ h16,
                                                            const _Float16* __restrict__ bpack,
                                                            const float* __restrict__ fc1b,
                                                            const float* __restrict__ fc2w,
                                                            const float* __restrict__ fc2b,
                                                            float* __restrict__ out, int E) {
    __shared__ _Float16 bsh[4096 * 8];   // 64 KB

    int tid = threadIdx.x;
    // cooperative stage: 4096 x 16B, coalesced
    {
        const int4* gsrc = (const int4*)bpack;
        int4* ldst = (int4*)bsh;
#pragma unroll
        for (int i = 0; i < 16; i++) ldst[tid + i * 256] = gsrc[tid + i * 256];
    }

    int w = tid >> 6;
    int lane = tid & 63;
    int m = lane & 15;        // A row (edge within tile)
    int kg = lane >> 4;       // k-group: feature = ks*32 + kg*8 + i
    int n0 = lane & 15;
    int rowg = lane >> 4;
    int tile0 = blockIdx.x * 16 + w * 4;   // first 16-edge tile of this wave
    const f16x8* bfr = ((const f16x8*)bsh) + lane;
    float b2 = fc2b[0];

    // hoisted epilogue constants
    float bb[8], ww[8];
#pragma unroll
    for (int nt = 0; nt < 8; nt++) {
        bb[nt] = fc1b[nt * 16 + n0];
        ww[nt] = fc2w[nt * 16 + n0];
    }

    auto LOAD = [&](int t, f16x8* xl, f16x8* yl) {
        int p = (tile0 + t) * 16 + m;
        int2 sd = (p < E) ? sdSorted[p] : make_int2(0, 0);
        const _Float16* px = h16 + (size_t)sd.x * 128 + kg * 8;
        const _Float16* py = h16 + (size_t)sd.y * 128 + kg * 8;
#pragma unroll
        for (int ks = 0; ks < 4; ks++) {
            xl[ks] = *(const f16x8*)(px + ks * 32);
            yl[ks] = *(const f16x8*)(py + ks * 32);
        }
    };

    auto COMPUTE = [&](int t, const f16x8* xl, const f16x8* yl) {
        f16x8 afrag[8];
#pragma unroll
        for (int ks = 0; ks < 4; ks++) {
            afrag[ks]     = xl[ks] * yl[ks];
            afrag[ks + 4] = xl[ks] - yl[ks];
        }
        f32x4 acc[8];
#pragma unroll
        for (int nt = 0; nt < 8; nt++) acc[nt] = (f32x4){bb[nt], bb[nt], bb[nt], bb[nt]};
#pragma unroll
        for (int ks = 0; ks < 8; ks++) {
#pragma unroll
            for (int nt = 0; nt < 8; nt++) {
                f16x8 b = bfr[(ks * 8 + nt) * 64];
                acc[nt] = __builtin_amdgcn_mfma_f32_16x16x32_f16(afrag[ks], b, acc[nt], 0, 0, 0);
            }
        }
        float partial[4] = {0.f, 0.f, 0.f, 0.f};
#pragma unroll
        for (int nt = 0; nt < 8; nt++) {
#pragma unroll
            for (int r = 0; r < 4; r++) {
                float z = fmaxf(acc[nt][r], 0.f);
                partial[r] = fmaf(z, ww[nt], partial[r]);
            }
        }
#pragma unroll
        for (int r = 0; r < 4; r++) {
            partial[r] += __shfl_xor(partial[r], 1);
            partial[r] += __shfl_xor(partial[r], 2);
            partial[r] += __shfl_xor(partial[r], 4);
            partial[r] += __shfl_xor(partial[r], 8);
        }
        if (n0 == 0) {
#pragma unroll
            for (int r = 0; r < 4; r++) {
                int qq = (tile0 + t) * 16 + rowg * 4 + r;
                if (qq < E) out[edgePerm[qq]] = 1.0f / (1.0f + expf(-(partial[r] + b2)));
            }
        }
    };

    // double-buffered pipeline over 4 tiles
    f16x8 xa[4], ya[4], xb[4], yb[4];
    LOAD(0, xa, ya);
    __syncthreads();            // bsh ready
    LOAD(1, xb, yb);
    COMPUTE(0, xa, ya);
    LOAD(2, xa, ya);
    COMPUTE(1, xb, yb);
    LOAD(3, xb, yb);
    COMPUTE(2, xa, ya);
    COMPUTE(3, xb, yb);
}

// ================= host =================
extern "C" void kernel_launch(void* const* d_in, const int* in_sizes, int n_in,
                              void* d_out, int out_size, void* d_ws, size_t ws_size,
                              hipStream_t stream) {
    const float* x    = (const float*)d_in[0];
    const int*   ei   = (const int*)d_in[1];
    const float* W1   = (const float*)d_in[2];
    const float* b1   = (const float*)d_in[3];
    const float* W2   = (const float*)d_in[4];
    const float* b2   = (const float*)d_in[5];
    const float* fc1w = (const float*)d_in[6];
    const float* fc1b = (const float*)d_in[7];
    const float* fc2w = (const float*)d_in[8];
    const float* fc2b = (const float*)d_in[9];

    int N = in_sizes[0] / 128;
    int E = in_sizes[1] / 2;
    const int* src = ei;
    const int* dst = ei + E;

    // ---- workspace layout ----
    char* ws = (char*)d_ws;
    size_t off = 0;
    auto alloc = [&](size_t bytes) { char* p = ws + off; off += (bytes + 255) & ~(size_t)255; return p; };
    int*      cnt       = (int*)     alloc((size_t)N * 4);
    int*      rowptr    = (int*)     alloc(((size_t)N + 1) * 4);
    int*      cursor    = (int*)     alloc((size_t)N * 4);
    int*      blockSums = (int*)     alloc(256 * 4);
    int2*     swPair    = (int2*)    alloc((size_t)E * 8);
    int2*     sdSorted  = (int2*)    alloc((size_t)E * 8);
    int*      edgePerm  = (int*)     alloc((size_t)E * 4);
    float*    dinv      = (float*)   alloc((size_t)N * 4);
    _Float16* bpack     = (_Float16*)alloc((size_t)4096 * 8 * 2);     // 64 KB
    float*    xw        = (float*)   alloc((size_t)N * 128 * 4);
    __bf16*   xw16      = (__bf16*)  alloc((size_t)N * 128 * 2);
    _Float16* h16       = (_Float16*)alloc((size_t)N * 128 * 2);

    int gN     = (N + THREADS - 1) / THREADS;
    int gE     = (E + THREADS - 1) / THREADS;
    int nchunk = (N + 1023) / 1024;
    int gGemm  = (N + 63) / 64;
    int gGath  = (N + 3) / 4;
    int gHead  = (E + 255) / 256;

    // ---- CSR build + degrees + B-pack ----
    hipMemsetAsync(cnt, 0, (size_t)N * 4, stream);
    k_hist<<<gE, THREADS, 0, stream>>>(dst, cnt, E);
    k_dinv<<<gN, THREADS, 0, stream>>>(cnt, dinv, N);
    k_scan1<<<nchunk, THREADS, 0, stream>>>(cnt, rowptr, blockSums, N);
    k_scan2<<<1, THREADS, 0, stream>>>(blockSums, rowptr, nchunk, N, E);
    k_scan3<<<gN, THREADS, 0, stream>>>(rowptr, blockSums, N);
    hipMemsetAsync(cursor, 0, (size_t)N * 4, stream);
    k_scatter<<<gE, THREADS, 0, stream>>>(src, dst, rowptr, dinv, cursor,
                                          swPair, sdSorted, edgePerm, E);
    k_pack_b<<<16, THREADS, 0, stream>>>(fc1w, bpack);

    // ---- layer 1 ----
    k_gemm128_f32<<<gGemm, THREADS, 0, stream>>>(x, W1, xw, xw16, N);
    k_gather_agg<<<gGath, THREADS, 0, stream>>>(rowptr, swPair, xw16, xw, dinv, b1, h16, N);

    // ---- layer 2 ----
    k_gemm128_f16<<<gGemm, THREADS, 0, stream>>>(h16, W2, xw, xw16, N);
    k_gather_agg<<<gGath, THREADS, 0, stream>>>(rowptr, swPair, xw16, xw, dinv, b2, h16, N);

    // ---- edge head (MFMA fp16, LDS B, pipelined 4 tiles/wave) ----
    k_edge_head_mfma<<<gHead, THREADS, 0, stream>>>(sdSorted, edgePerm,
                                                    h16, bpack, fc1b, fc2w, fc2b,
                                                    (float*)d_out, E);
}

// Round 14
// 494.658 us; speedup vs baseline: 1.4032x; 1.1338x over previous
//
#include <hip/hip_runtime.h>

#define THREADS 256

typedef __bf16    bf16x8 __attribute__((ext_vector_type(8)));
typedef _Float16  f16x8  __attribute__((ext_vector_type(8)));
typedef float     f32x4  __attribute__((ext_vector_type(4)));

// ================= CSR build: histogram -> scan -> scatter =================

__global__ __launch_bounds__(THREADS) void k_hist(const int* __restrict__ dst,
                                                  int* __restrict__ cnt, int E) {
    int e = blockIdx.x * THREADS + threadIdx.x;
    if (e < E) atomicAdd(&cnt[dst[e]], 1);
}

__global__ __launch_bounds__(THREADS) void k_dinv(const int* __restrict__ cnt,
                                                  float* __restrict__ dinv, int n) {
    int i = blockIdx.x * THREADS + threadIdx.x;
    if (i < n) dinv[i] = rsqrtf((float)cnt[i] + 1.0f);
}

__global__ __launch_bounds__(THREADS) void k_scan1(const int* __restrict__ cnt,
                                                   int* __restrict__ rowptr,
                                                   int* __restrict__ blockSums, int n) {
    __shared__ int part[THREADS];
    int tid = threadIdx.x;
    int base = blockIdx.x * 1024 + tid * 4;
    int v0 = (base + 0 < n) ? cnt[base + 0] : 0;
    int v1 = (base + 1 < n) ? cnt[base + 1] : 0;
    int v2 = (base + 2 < n) ? cnt[base + 2] : 0;
    int v3 = (base + 3 < n) ? cnt[base + 3] : 0;
    part[tid] = v0 + v1 + v2 + v3;
    __syncthreads();
    for (int off = 1; off < THREADS; off <<= 1) {
        int t = 0;
        if (tid >= off) t = part[tid - off];
        __syncthreads();
        if (tid >= off) part[tid] += t;
        __syncthreads();
    }
    int excl = (tid == 0) ? 0 : part[tid - 1];
    if (tid == THREADS - 1) blockSums[blockIdx.x] = part[THREADS - 1];
    int run = excl;
    if (base + 0 < n) rowptr[base + 0] = run; run += v0;
    if (base + 1 < n) rowptr[base + 1] = run; run += v1;
    if (base + 2 < n) rowptr[base + 2] = run; run += v2;
    if (base + 3 < n) rowptr[base + 3] = run;
}

__global__ __launch_bounds__(THREADS) void k_scan2(int* __restrict__ blockSums,
                                                   int* __restrict__ rowptr,
                                                   int nchunks, int n, int E) {
    __shared__ int part[THREADS];
    int tid = threadIdx.x;
    int v = (tid < nchunks) ? blockSums[tid] : 0;
    part[tid] = v;
    __syncthreads();
    for (int off = 1; off < THREADS; off <<= 1) {
        int t = 0;
        if (tid >= off) t = part[tid - off];
        __syncthreads();
        if (tid >= off) part[tid] += t;
        __syncthreads();
    }
    int excl = (tid == 0) ? 0 : part[tid - 1];
    if (tid < nchunks) blockSums[tid] = excl;
    if (tid == 0) rowptr[n] = E;
}

__global__ __launch_bounds__(THREADS) void k_scan3(int* __restrict__ rowptr,
                                                   const int* __restrict__ blockSums, int n) {
    int i = blockIdx.x * THREADS + threadIdx.x;
    if (i < n) rowptr[i] += blockSums[i >> 10];
}

// writes: swPair {src, dinv[src]}, sdSorted {src,dst}, edgePerm
__global__ __launch_bounds__(THREADS) void k_scatter(const int* __restrict__ src,
                                                     const int* __restrict__ dst,
                                                     const int* __restrict__ rowptr,
                                                     const float* __restrict__ dinv,
                                                     int* __restrict__ cursor,
                                                     int2* __restrict__ swPair,
                                                     int2* __restrict__ sdSorted,
                                                     int* __restrict__ edgePerm, int E) {
    int e = blockIdx.x * THREADS + threadIdx.x;
    if (e >= E) return;
    int d = dst[e];
    int s = src[e];
    int pos = rowptr[d] + atomicAdd(&cursor[d], 1);
    swPair[pos] = make_int2(s, __float_as_int(dinv[s]));
    sdSorted[pos] = make_int2(s, d);
    edgePerm[pos] = e;
}

// ========= W-pack: W [128][128] f32 (x2) -> MFMA B-fragments fp16 =========
// frag fi = ks*8+nt (ks<4, nt<8); lane elem i: W[ks*32+(lane>>4)*8+i][nt*16+(lane&15)]
__global__ __launch_bounds__(THREADS) void k_pack_w(const float* __restrict__ W1,
                                                    const float* __restrict__ W2,
                                                    _Float16* __restrict__ wp1,
                                                    _Float16* __restrict__ wp2) {
    int t = blockIdx.x * THREADS + threadIdx.x;   // 0..4095
    const float* W = (t < 2048) ? W1 : W2;
    _Float16* wp = (t < 2048) ? wp1 : wp2;
    int tt = t & 2047;
    int lane = tt & 63;
    int fi = tt >> 6;          // ks*8+nt
    int nt = fi & 7, ks = fi >> 3;
    int krow = ks * 32 + (lane >> 4) * 8;
    int col = nt * 16 + (lane & 15);
    f16x8 v;
#pragma unroll
    for (int i = 0; i < 8; i++) v[i] = (_Float16)W[(size_t)(krow + i) * 128 + col];
    *(f16x8*)(wp + (size_t)tt * 8) = v;
}

// ========= MFMA GEMM (f32 A): C16[M][128] = bf16( A[M][128] @ W ) =========
// 4 waves/block, 4 tiles(16 rows)/wave; W fragments staged in 32KB LDS.
__global__ __launch_bounds__(THREADS) void k_gemm_mfma_f32(const float* __restrict__ A,
                                                           const _Float16* __restrict__ wpack,
                                                           __bf16* __restrict__ C16, int M) {
    __shared__ _Float16 wsh[2048 * 8];   // 32 KB
    int tid = threadIdx.x;
    {
        const int4* g = (const int4*)wpack;
        int4* l = (int4*)wsh;
#pragma unroll
        for (int i = 0; i < 8; i++) l[tid + i * 256] = g[tid + i * 256];
    }
    int w = tid >> 6, lane = tid & 63;
    int m = lane & 15, kg = lane >> 4;
    int n0 = lane & 15, rowg = lane >> 4;
    int tile0 = blockIdx.x * 16 + w * 4;
    __syncthreads();
    const f16x8* wfr = ((const f16x8*)wsh) + lane;

    for (int t = 0; t < 4; t++) {
        int row = (tile0 + t) * 16 + m;
        f16x8 a[4];
        if (row < M) {
            const float* pa = A + (size_t)row * 128 + kg * 8;
#pragma unroll
            for (int ks = 0; ks < 4; ks++) {
                float4 lo = *(const float4*)(pa + ks * 32);
                float4 hi = *(const float4*)(pa + ks * 32 + 4);
                f16x8 v;
                v[0] = (_Float16)lo.x; v[1] = (_Float16)lo.y;
                v[2] = (_Float16)lo.z; v[3] = (_Float16)lo.w;
                v[4] = (_Float16)hi.x; v[5] = (_Float16)hi.y;
                v[6] = (_Float16)hi.z; v[7] = (_Float16)hi.w;
                a[ks] = v;
            }
        } else {
#pragma unroll
            for (int ks = 0; ks < 4; ks++) { f16x8 z = {}; a[ks] = z; }
        }
        f32x4 acc[8];
#pragma unroll
        for (int i = 0; i < 8; i++) acc[i] = (f32x4){0.f, 0.f, 0.f, 0.f};
#pragma unroll
        for (int ks = 0; ks < 4; ks++) {
#pragma unroll
            for (int nt = 0; nt < 8; nt++) {
                f16x8 b = wfr[(ks * 8 + nt) * 64];
                acc[nt] = __builtin_amdgcn_mfma_f32_16x16x32_f16(a[ks], b, acc[nt], 0, 0, 0);
            }
        }
#pragma unroll
        for (int nt = 0; nt < 8; nt++) {
#pragma unroll
            for (int r = 0; r < 4; r++) {
                int ro = (tile0 + t) * 16 + rowg * 4 + r;
                if (ro < M) C16[(size_t)ro * 128 + nt * 16 + n0] = (__bf16)acc[nt][r];
            }
        }
    }
}

// ========= MFMA GEMM (fp16 A): same, A loaded directly from h16 =========
__global__ __launch_bounds__(THREADS) void k_gemm_mfma_f16(const _Float16* __restrict__ A,
                                                           const _Float16* __restrict__ wpack,
                                                           __bf16* __restrict__ C16, int M) {
    __shared__ _Float16 wsh[2048 * 8];   // 32 KB
    int tid = threadIdx.x;
    {
        const int4* g = (const int4*)wpack;
        int4* l = (int4*)wsh;
#pragma unroll
        for (int i = 0; i < 8; i++) l[tid + i * 256] = g[tid + i * 256];
    }
    int w = tid >> 6, lane = tid & 63;
    int m = lane & 15, kg = lane >> 4;
    int n0 = lane & 15, rowg = lane >> 4;
    int tile0 = blockIdx.x * 16 + w * 4;
    __syncthreads();
    const f16x8* wfr = ((const f16x8*)wsh) + lane;

    for (int t = 0; t < 4; t++) {
        int row = (tile0 + t) * 16 + m;
        f16x8 a[4];
        if (row < M) {
            const _Float16* pa = A + (size_t)row * 128 + kg * 8;
#pragma unroll
            for (int ks = 0; ks < 4; ks++) a[ks] = *(const f16x8*)(pa + ks * 32);
        } else {
#pragma unroll
            for (int ks = 0; ks < 4; ks++) { f16x8 z = {}; a[ks] = z; }
        }
        f32x4 acc[8];
#pragma unroll
        for (int i = 0; i < 8; i++) acc[i] = (f32x4){0.f, 0.f, 0.f, 0.f};
#pragma unroll
        for (int ks = 0; ks < 4; ks++) {
#pragma unroll
            for (int nt = 0; nt < 8; nt++) {
                f16x8 b = wfr[(ks * 8 + nt) * 64];
                acc[nt] = __builtin_amdgcn_mfma_f32_16x16x32_f16(a[ks], b, acc[nt], 0, 0, 0);
            }
        }
#pragma unroll
        for (int nt = 0; nt < 8; nt++) {
#pragma unroll
            for (int r = 0; r < 4; r++) {
                int ro = (tile0 + t) * 16 + rowg * 4 + r;
                if (ro < M) C16[(size_t)ro * 128 + nt * 16 + n0] = (__bf16)acc[nt][r];
            }
        }
    }
}

// ===== gather-aggregate (bf16 gather, self-term from xw16, fp16 h out) =====
__global__ __launch_bounds__(THREADS) void k_gather_agg(const int* __restrict__ rowptr,
                                                        const int2* __restrict__ swPair,
                                                        const __bf16* __restrict__ xw16,
                                                        const float* __restrict__ dinv,
                                                        const float* __restrict__ bias,
                                                        _Float16* __restrict__ h16, int n) {
    int node = blockIdx.x * 4 + (threadIdx.x >> 6);
    int lane = threadIdx.x & 63;
    int q = lane >> 4;
    int c = lane & 15;          // channels c*8 .. c*8+7
    if (node >= n) return;
    int beg = rowptr[node], end = rowptr[node + 1];
    float di = dinv[node];

    float acc[8];
#pragma unroll
    for (int i = 0; i < 8; i++) acc[i] = 0.f;

    int j = beg;
    for (; j + 15 < end; j += 16) {
        int2 pw0 = swPair[j + q];
        int2 pw1 = swPair[j + 4 + q];
        int2 pw2 = swPair[j + 8 + q];
        int2 pw3 = swPair[j + 12 + q];
        bf16x8 v0 = *(const bf16x8*)(xw16 + (size_t)pw0.x * 128 + c * 8);
        bf16x8 v1 = *(const bf16x8*)(xw16 + (size_t)pw1.x * 128 + c * 8);
        bf16x8 v2 = *(const bf16x8*)(xw16 + (size_t)pw2.x * 128 + c * 8);
        bf16x8 v3 = *(const bf16x8*)(xw16 + (size_t)pw3.x * 128 + c * 8);
        float w0 = __int_as_float(pw0.y);
        float w1 = __int_as_float(pw1.y);
        float w2 = __int_as_float(pw2.y);
        float w3 = __int_as_float(pw3.y);
#pragma unroll
        for (int i = 0; i < 8; i++) {
            acc[i] = fmaf((float)v0[i], w0, acc[i]);
            acc[i] = fmaf((float)v1[i], w1, acc[i]);
            acc[i] = fmaf((float)v2[i], w2, acc[i]);
            acc[i] = fmaf((float)v3[i], w3, acc[i]);
        }
    }
    for (; j + 7 < end; j += 8) {
        int2 pw0 = swPair[j + q];
        int2 pw1 = swPair[j + 4 + q];
        bf16x8 v0 = *(const bf16x8*)(xw16 + (size_t)pw0.x * 128 + c * 8);
        bf16x8 v1 = *(const bf16x8*)(xw16 + (size_t)pw1.x * 128 + c * 8);
        float w0 = __int_as_float(pw0.y);
        float w1 = __int_as_float(pw1.y);
#pragma unroll
        for (int i = 0; i < 8; i++) {
            acc[i] = fmaf((float)v0[i], w0, acc[i]);
            acc[i] = fmaf((float)v1[i], w1, acc[i]);
        }
    }
    for (; j + 3 < end; j += 4) {
        int2 pw = swPair[j + q];
        bf16x8 v = *(const bf16x8*)(xw16 + (size_t)pw.x * 128 + c * 8);
        float w = __int_as_float(pw.y);
#pragma unroll
        for (int i = 0; i < 8; i++) acc[i] = fmaf((float)v[i], w, acc[i]);
    }
    int rem = end - j;
    if (q < rem) {
        int2 pw = swPair[j + q];
        bf16x8 v = *(const bf16x8*)(xw16 + (size_t)pw.x * 128 + c * 8);
        float w = __int_as_float(pw.y);
#pragma unroll
        for (int i = 0; i < 8; i++) acc[i] = fmaf((float)v[i], w, acc[i]);
    }

    // merge quarters
#pragma unroll
    for (int i = 0; i < 8; i++) {
        acc[i] += __shfl_xor(acc[i], 16);
        acc[i] += __shfl_xor(acc[i], 32);
    }

    if (q == 0) {
        bf16x8 sv = *(const bf16x8*)(xw16 + (size_t)node * 128 + c * 8);
        float4 b0 = *(const float4*)(bias + c * 8);
        float4 b1 = *(const float4*)(bias + c * 8 + 4);
        float bb[8] = {b0.x, b0.y, b0.z, b0.w, b1.x, b1.y, b1.z, b1.w};
        float dd = di * di;
        f16x8 r16;
#pragma unroll
        for (int i = 0; i < 8; i++) {
            float r = fmaf(acc[i], di, fmaf((float)sv[i], dd, bb[i]));
            r16[i] = (_Float16)fmaxf(r, 0.f);
        }
        *(f16x8*)(h16 + (size_t)node * 128 + c * 8) = r16;
    }
}

// ================= B-pack: fc1w [256][128] f32 -> MFMA B-fragments fp16 =================
__global__ __launch_bounds__(THREADS) void k_pack_b(const float* __restrict__ fc1w,
                                                    _Float16* __restrict__ bpack) {
    int t = blockIdx.x * THREADS + threadIdx.x;   // 0..4095
    int lane = t & 63;
    int fi = t >> 6;          // ks*8+nt
    int nt = fi & 7, ks = fi >> 3;
    int krow = ks * 32 + (lane >> 4) * 8;
    int col = nt * 16 + (lane & 15);
    f16x8 v;
#pragma unroll
    for (int i = 0; i < 8; i++) v[i] = (_Float16)fc1w[(size_t)(krow + i) * 128 + col];
    *(f16x8*)(bpack + (size_t)t * 8) = v;
}

// ================= edge head (MFMA fp16, LDS B, 4 tiles/wave, dbuf pipeline) ====
__global__ __launch_bounds__(THREADS) void k_edge_head_mfma(const int2* __restrict__ sdSorted,
                                                            const int* __restrict__ edgePerm,
                                                            const _Float16* __restrict__ h16,
                                                            const _Float16* __restrict__ bpack,
                                                            const float* __restrict__ fc1b,
                                                            const float* __restrict__ fc2w,
                                                            const float* __restrict__ fc2b,
                                                            float* __restrict__ out, int E) {
    __shared__ _Float16 bsh[4096 * 8];   // 64 KB

    int tid = threadIdx.x;
    {
        const int4* gsrc = (const int4*)bpack;
        int4* ldst = (int4*)bsh;
#pragma unroll
        for (int i = 0; i < 16; i++) ldst[tid + i * 256] = gsrc[tid + i * 256];
    }

    int w = tid >> 6;
    int lane = tid & 63;
    int m = lane & 15;
    int kg = lane >> 4;
    int n0 = lane & 15;
    int rowg = lane >> 4;
    int tile0 = blockIdx.x * 16 + w * 4;
    const f16x8* bfr = ((const f16x8*)bsh) + lane;
    float b2 = fc2b[0];

    float bb[8], ww[8];
#pragma unroll
    for (int nt = 0; nt < 8; nt++) {
        bb[nt] = fc1b[nt * 16 + n0];
        ww[nt] = fc2w[nt * 16 + n0];
    }

    auto LOAD = [&](int t, f16x8* xl, f16x8* yl) {
        int p = (tile0 + t) * 16 + m;
        int2 sd = (p < E) ? sdSorted[p] : make_int2(0, 0);
        const _Float16* px = h16 + (size_t)sd.x * 128 + kg * 8;
        const _Float16* py = h16 + (size_t)sd.y * 128 + kg * 8;
#pragma unroll
        for (int ks = 0; ks < 4; ks++) {
            xl[ks] = *(const f16x8*)(px + ks * 32);
            yl[ks] = *(const f16x8*)(py + ks * 32);
        }
    };

    auto COMPUTE = [&](int t, const f16x8* xl, const f16x8* yl) {
        f16x8 afrag[8];
#pragma unroll
        for (int ks = 0; ks < 4; ks++) {
            afrag[ks]     = xl[ks] * yl[ks];
            afrag[ks + 4] = xl[ks] - yl[ks];
        }
        f32x4 acc[8];
#pragma unroll
        for (int nt = 0; nt < 8; nt++) acc[nt] = (f32x4){bb[nt], bb[nt], bb[nt], bb[nt]};
#pragma unroll
        for (int ks = 0; ks < 8; ks++) {
#pragma unroll
            for (int nt = 0; nt < 8; nt++) {
                f16x8 b = bfr[(ks * 8 + nt) * 64];
                acc[nt] = __builtin_amdgcn_mfma_f32_16x16x32_f16(afrag[ks], b, acc[nt], 0, 0, 0);
            }
        }
        float partial[4] = {0.f, 0.f, 0.f, 0.f};
#pragma unroll
        for (int nt = 0; nt < 8; nt++) {
#pragma unroll
            for (int r = 0; r < 4; r++) {
                float z = fmaxf(acc[nt][r], 0.f);
                partial[r] = fmaf(z, ww[nt], partial[r]);
            }
        }
#pragma unroll
        for (int r = 0; r < 4; r++) {
            partial[r] += __shfl_xor(partial[r], 1);
            partial[r] += __shfl_xor(partial[r], 2);
            partial[r] += __shfl_xor(partial[r], 4);
            partial[r] += __shfl_xor(partial[r], 8);
        }
        if (n0 == 0) {
#pragma unroll
            for (int r = 0; r < 4; r++) {
                int qq = (tile0 + t) * 16 + rowg * 4 + r;
                if (qq < E) out[edgePerm[qq]] = 1.0f / (1.0f + expf(-(partial[r] + b2)));
            }
        }
    };

    f16x8 xa[4], ya[4], xb[4], yb[4];
    LOAD(0, xa, ya);
    __syncthreads();
    LOAD(1, xb, yb);
    COMPUTE(0, xa, ya);
    LOAD(2, xa, ya);
    COMPUTE(1, xb, yb);
    LOAD(3, xb, yb);
    COMPUTE(2, xa, ya);
    COMPUTE(3, xb, yb);
}

// ================= host =================
extern "C" void kernel_launch(void* const* d_in, const int* in_sizes, int n_in,
                              void* d_out, int out_size, void* d_ws, size_t ws_size,
                              hipStream_t stream) {
    const float* x    = (const float*)d_in[0];
    const int*   ei   = (const int*)d_in[1];
    const float* W1   = (const float*)d_in[2];
    const float* b1   = (const float*)d_in[3];
    const float* W2   = (const float*)d_in[4];
    const float* b2   = (const float*)d_in[5];
    const float* fc1w = (const float*)d_in[6];
    const float* fc1b = (const float*)d_in[7];
    const float* fc2w = (const float*)d_in[8];
    const float* fc2b = (const float*)d_in[9];

    int N = in_sizes[0] / 128;
    int E = in_sizes[1] / 2;
    const int* src = ei;
    const int* dst = ei + E;

    // ---- workspace layout ----
    char* ws = (char*)d_ws;
    size_t off = 0;
    auto alloc = [&](size_t bytes) { char* p = ws + off; off += (bytes + 255) & ~(size_t)255; return p; };
    int*      cnt       = (int*)     alloc((size_t)N * 4);
    int*      rowptr    = (int*)     alloc(((size_t)N + 1) * 4);
    int*      cursor    = (int*)     alloc((size_t)N * 4);
    int*      blockSums = (int*)     alloc(256 * 4);
    int2*     swPair    = (int2*)    alloc((size_t)E * 8);
    int2*     sdSorted  = (int2*)    alloc((size_t)E * 8);
    int*      edgePerm  = (int*)     alloc((size_t)E * 4);
    float*    dinv      = (float*)   alloc((size_t)N * 4);
    _Float16* bpack     = (_Float16*)alloc((size_t)4096 * 8 * 2);   // 64 KB
    _Float16* wp1       = (_Float16*)alloc((size_t)2048 * 8 * 2);   // 32 KB
    _Float16* wp2       = (_Float16*)alloc((size_t)2048 * 8 * 2);   // 32 KB
    __bf16*   xw16      = (__bf16*)  alloc((size_t)N * 128 * 2);
    _Float16* h16       = (_Float16*)alloc((size_t)N * 128 * 2);

    int gN     = (N + THREADS - 1) / THREADS;
    int gE     = (E + THREADS - 1) / THREADS;
    int nchunk = (N + 1023) / 1024;
    int nTileG = (N + 15) / 16;
    int gGemm  = (nTileG + 15) / 16;
    int gGath  = (N + 3) / 4;
    int gHead  = (E + 255) / 256;

    // ---- CSR build + degrees + packs ----
    hipMemsetAsync(cnt, 0, (size_t)N * 4, stream);
    k_hist<<<gE, THREADS, 0, stream>>>(dst, cnt, E);
    k_dinv<<<gN, THREADS, 0, stream>>>(cnt, dinv, N);
    k_scan1<<<nchunk, THREADS, 0, stream>>>(cnt, rowptr, blockSums, N);
    k_scan2<<<1, THREADS, 0, stream>>>(blockSums, rowptr, nchunk, N, E);
    k_scan3<<<gN, THREADS, 0, stream>>>(rowptr, blockSums, N);
    hipMemsetAsync(cursor, 0, (size_t)N * 4, stream);
    k_scatter<<<gE, THREADS, 0, stream>>>(src, dst, rowptr, dinv, cursor,
                                          swPair, sdSorted, edgePerm, E);
    k_pack_b<<<16, THREADS, 0, stream>>>(fc1w, bpack);
    k_pack_w<<<16, THREADS, 0, stream>>>(W1, W2, wp1, wp2);

    // ---- layer 1 (MFMA GEMM) ----
    k_gemm_mfma_f32<<<gGemm, THREADS, 0, stream>>>(x, wp1, xw16, N);
    k_gather_agg<<<gGath, THREADS, 0, stream>>>(rowptr, swPair, xw16, dinv, b1, h16, N);

    // ---- layer 2 (MFMA GEMM) ----
    k_gemm_mfma_f16<<<gGemm, THREADS, 0, stream>>>(h16, wp2, xw16, N);
    k_gather_agg<<<gGath, THREADS, 0, stream>>>(rowptr, swPair, xw16, dinv, b2, h16, N);

    // ---- edge head (MFMA fp16, LDS B, pipelined) ----
    k_edge_head_mfma<<<gHead, THREADS, 0, stream>>>(sdSorted, edgePerm,
                                                    h16, bpack, fc1b, fc2w, fc2b,
                                                    (float*)d_out, E);
}